// Round 1
// baseline (1953.752 us; speedup 1.0000x reference)
//
#include <hip/hip_runtime.h>
#include <math.h>

#define RR 3
#define NTOT 100000
#define NN0 80000
#define NN1 20000
#define NB 4096
#define NE1 300000
#define NE2 65536
#define FIN 128
#define HC1 256   // layer1: 2 heads x 128
#define HC2 128   // layer2: 1 head x 128

__device__ __forceinline__ float wave_red_sum(float v) {
    #pragma unroll
    for (int off = 32; off >= 1; off >>= 1) v += __shfl_xor(v, off, 64);
    return v;
}

// ---------- GEMM: out0 = x@W0+b0, out1 = x@W1+b1, optional row gather ----------
// x: [*, ldx] f32, rows selected by gidx (or identity). W: [K,N]. out: [M,N].
template<int K, int N, int ROWS>
__global__ void __launch_bounds__(256)
gemm2k(const float* __restrict__ x, int ldx, const int* __restrict__ gidx, int M,
       const float* __restrict__ W0, const float* __restrict__ b0, float* __restrict__ out0,
       const float* __restrict__ W1, const float* __restrict__ b1, float* __restrict__ out1)
{
    __shared__ float xs[ROWS][K];
    const int tid = threadIdx.x;
    const int rb = blockIdx.x * ROWS;
    for (int i = tid; i < ROWS * K; i += 256) {
        int rr = i / K, kk = i - rr * K;
        int gr = rb + rr;
        float val = 0.f;
        if (gr < M) {
            int srow = gidx ? gidx[gr] : gr;
            val = x[(size_t)srow * ldx + kk];
        }
        xs[rr][kk] = val;
    }
    __syncthreads();
    constexpr int GROUPS = 256 / N;      // 1 (N=256) or 2 (N=128)
    constexpr int RPT = ROWS / GROUPS;   // rows per thread
    const int col = tid % N;
    const int r0 = (tid / N) * RPT;
    float acc0[RPT], acc1[RPT];
    #pragma unroll
    for (int r = 0; r < RPT; ++r) { acc0[r] = 0.f; acc1[r] = 0.f; }
    for (int k = 0; k < K; k += 4) {
        float w0[4], w1[4];
        #pragma unroll
        for (int j = 0; j < 4; ++j) {
            w0[j] = W0[(size_t)(k + j) * N + col];
            w1[j] = W1[(size_t)(k + j) * N + col];
        }
        #pragma unroll
        for (int r = 0; r < RPT; ++r) {
            float4 xv = *(const float4*)&xs[r0 + r][k];
            acc0[r] = fmaf(xv.x, w0[0], acc0[r]);
            acc0[r] = fmaf(xv.y, w0[1], acc0[r]);
            acc0[r] = fmaf(xv.z, w0[2], acc0[r]);
            acc0[r] = fmaf(xv.w, w0[3], acc0[r]);
            acc1[r] = fmaf(xv.x, w1[0], acc1[r]);
            acc1[r] = fmaf(xv.y, w1[1], acc1[r]);
            acc1[r] = fmaf(xv.z, w1[2], acc1[r]);
            acc1[r] = fmaf(xv.w, w1[3], acc1[r]);
        }
    }
    const float bb0 = b0[col], bb1 = b1[col];
    #pragma unroll
    for (int r = 0; r < RPT; ++r) {
        int row = rb + r0 + r;
        if (row < M) {
            out0[(size_t)row * N + col] = acc0[r] + bb0;
            out1[(size_t)row * N + col] = acc1[r] + bb1;
        }
    }
}

// ---------- per-edge attention logits: alpha[e,h] = <q[dst,h,:], k[src,h,:]>/sqrt(C) ----------
template<int HC, int H>
__global__ void __launch_bounds__(256)
edge_alpha(const int* __restrict__ src, const int* __restrict__ dst, int E,
           const float* __restrict__ q, const float* __restrict__ k,
           float* __restrict__ alpha)
{
    constexpr int EPL = HC / 64;   // elems per lane
    constexpr int C = HC / H;
    constexpr int GL = 64 / H;     // lanes per head group
    const int lane = threadIdx.x & 63;
    const int wid = (blockIdx.x * blockDim.x + threadIdx.x) >> 6;
    const int nw = (gridDim.x * blockDim.x) >> 6;
    const float scale = rsqrtf((float)C);
    for (int e = wid; e < E; e += nw) {
        const int s = src[e], d = dst[e];
        const float* qp = q + (size_t)d * HC + lane * EPL;
        const float* kp = k + (size_t)s * HC + lane * EPL;
        float part;
        if constexpr (EPL == 4) {
            float4 qv = *(const float4*)qp, kv = *(const float4*)kp;
            part = qv.x*kv.x + qv.y*kv.y + qv.z*kv.z + qv.w*kv.w;
        } else {
            float2 qv = *(const float2*)qp, kv = *(const float2*)kp;
            part = qv.x*kv.x + qv.y*kv.y;
        }
        #pragma unroll
        for (int off = GL/2; off >= 1; off >>= 1) part += __shfl_xor(part, off, 64);
        if ((lane & (GL-1)) == 0)
            alpha[(size_t)e*H + lane/GL] = part * scale;
    }
}

// ---------- CSR helpers ----------
__global__ void hist_k(const int* __restrict__ dst, int E, int* __restrict__ cnt) {
    for (int e = blockIdx.x*blockDim.x + threadIdx.x; e < E; e += gridDim.x*blockDim.x)
        atomicAdd(&cnt[dst[e]], 1);
}
__global__ void __launch_bounds__(256)
exscan_k(const int* __restrict__ cnt, int n, int* __restrict__ offs, int* __restrict__ cur) {
    __shared__ int ps[256];
    const int tid = threadIdx.x;
    const int chunk = (n + 255) / 256;
    const int lo = tid * chunk;
    const int hi = min(lo + chunk, n);
    int s = 0;
    for (int i = lo; i < hi; ++i) s += cnt[i];
    ps[tid] = s;
    __syncthreads();
    for (int off = 1; off < 256; off <<= 1) {
        int v = (tid >= off) ? ps[tid - off] : 0;
        __syncthreads();
        ps[tid] += v;
        __syncthreads();
    }
    int run = (tid == 0) ? 0 : ps[tid - 1];
    for (int i = lo; i < hi; ++i) { offs[i] = run; cur[i] = run; run += cnt[i]; }
    if (tid == 255) offs[n] = ps[255];
}
__global__ void scatter_k(const int* __restrict__ dst, int E, int* __restrict__ cur, int* __restrict__ elist) {
    for (int e = blockIdx.x*blockDim.x + threadIdx.x; e < E; e += gridDim.x*blockDim.x) {
        int pos = atomicAdd(&cur[dst[e]], 1);
        elist[pos] = e;
    }
}

// ---------- per-node softmax-aggregate (layer1: H=2, C=128) ----------
__global__ void __launch_bounds__(64)
agg_l1(const int* __restrict__ offs, const int* __restrict__ elist,
       const int* __restrict__ src, const float* __restrict__ alpha,
       const float* __restrict__ v, float* __restrict__ out)
{
    const int n = blockIdx.x;
    const int lane = threadIdx.x;
    const int c0 = lane * 4;
    const int hd = c0 >> 7;
    const int lo = offs[n], hi = offs[n+1];
    float m = -INFINITY;
    for (int i = lo; i < hi; ++i)
        m = fmaxf(m, alpha[(size_t)elist[i]*2 + hd]);
    float s = 0.f;
    float a0=0.f, a1=0.f, a2=0.f, a3=0.f;
    for (int i = lo; i < hi; ++i) {
        int e = elist[i];
        float p = __expf(alpha[(size_t)e*2 + hd] - m);
        s += p;
        const float4 vv = *(const float4*)(v + (size_t)src[e]*HC1 + c0);
        a0 = fmaf(p, vv.x, a0); a1 = fmaf(p, vv.y, a1);
        a2 = fmaf(p, vv.z, a2); a3 = fmaf(p, vv.w, a3);
    }
    const float inv = (s > 0.f) ? 1.f/s : 0.f;
    float4 o = { a0*inv, a1*inv, a2*inv, a3*inv };
    *(float4*)(out + (size_t)n*HC1 + c0) = o;
}

// ---------- per-node softmax-aggregate (layer2: H=1, C=128) ----------
__global__ void __launch_bounds__(64)
agg_l2(const int* __restrict__ offs, const int* __restrict__ elist,
       const int* __restrict__ src, const float* __restrict__ alpha,
       const float* __restrict__ v, float* __restrict__ out)
{
    const int n = blockIdx.x;
    const int lane = threadIdx.x;
    const int c0 = lane * 2;
    const int lo = offs[n], hi = offs[n+1];
    float m = -INFINITY;
    for (int i = lo; i < hi; ++i)
        m = fmaxf(m, alpha[elist[i]]);
    float s = 0.f; float a0=0.f, a1=0.f;
    for (int i = lo; i < hi; ++i) {
        int e = elist[i];
        float p = __expf(alpha[e] - m);
        s += p;
        const float2 vv = *(const float2*)(v + (size_t)src[e]*HC2 + c0);
        a0 = fmaf(p, vv.x, a0); a1 = fmaf(p, vv.y, a1);
    }
    const float inv = (s > 0.f) ? 1.f/s : 0.f;
    float2 o = { a0*inv, a1*inv };
    *(float2*)(out + (size_t)n*HC2 + c0) = o;
}

// ---------- layer1 epilogue: beta gate + BN(eval) + ELU ----------
__global__ void __launch_bounds__(64)
beta_bn_elu(const float* __restrict__ att, const float* __restrict__ xr,
            const float* __restrict__ wb,
            const float* __restrict__ g, const float* __restrict__ bb,
            const float* __restrict__ mean, const float* __restrict__ var,
            float* __restrict__ h)
{
    const int n = blockIdx.x;
    const int lane = threadIdx.x;
    const int c0 = lane * 4;
    float4 o4 = *(const float4*)(att + (size_t)n*HC1 + c0);
    float4 x4 = *(const float4*)(xr + (size_t)n*HC1 + c0);
    float oo[4] = {o4.x,o4.y,o4.z,o4.w};
    float xx[4] = {x4.x,x4.y,x4.z,x4.w};
    float d = 0.f;
    #pragma unroll
    for (int j = 0; j < 4; ++j) {
        int c = c0 + j;
        d += oo[j]*wb[c] + xx[j]*wb[HC1 + c] + (oo[j]-xx[j])*wb[2*HC1 + c];
    }
    d = wave_red_sum(d);
    const float beta = 1.f / (1.f + __expf(-d));
    #pragma unroll
    for (int j = 0; j < 4; ++j) {
        int c = c0 + j;
        float hv = beta*xx[j] + (1.f-beta)*oo[j];
        hv = (hv - mean[c]) * rsqrtf(var[c] + 1e-5f) * g[c] + bb[c];
        hv = hv > 0.f ? hv : expm1f(hv);
        h[(size_t)n*HC1 + c] = hv;
    }
}

// ---------- layer2 epilogue: beta gate + strided output write ----------
__global__ void __launch_bounds__(64)
beta_out(const float* __restrict__ att, const float* __restrict__ xr,
         const float* __restrict__ wb, float* __restrict__ outp, int colofs)
{
    const int n = blockIdx.x;
    const int lane = threadIdx.x;
    const int c0 = lane * 2;
    float2 o = *(const float2*)(att + (size_t)n*HC2 + c0);
    float2 x = *(const float2*)(xr + (size_t)n*HC2 + c0);
    float d = o.x*wb[c0] + o.y*wb[c0+1]
            + x.x*wb[HC2+c0] + x.y*wb[HC2+c0+1]
            + (o.x-x.x)*wb[2*HC2+c0] + (o.y-x.y)*wb[2*HC2+c0+1];
    d = wave_red_sum(d);
    const float beta = 1.f/(1.f+__expf(-d));
    outp[(size_t)n*(RR*HC2) + colofs + c0]     = beta*x.x + (1.f-beta)*o.x;
    outp[(size_t)n*(RR*HC2) + colofs + c0 + 1] = beta*x.y + (1.f-beta)*o.y;
}

extern "C" void kernel_launch(void* const* d_in, const int* in_sizes, int n_in,
                              void* d_out, int out_size, void* d_ws, size_t ws_size,
                              hipStream_t stream)
{
    const float* features = (const float*)d_in[0];
    const int*   n_ids    = (const int*)d_in[1];
    const int*   ei1      = (const int*)d_in[2];
    const int*   ei2      = (const int*)d_in[3];
    const float* wq1 = (const float*)d_in[4];  const float* bq1 = (const float*)d_in[5];
    const float* wk1 = (const float*)d_in[6];  const float* bk1 = (const float*)d_in[7];
    const float* wv1 = (const float*)d_in[8];  const float* bv1 = (const float*)d_in[9];
    const float* ws1 = (const float*)d_in[10]; const float* bs1 = (const float*)d_in[11];
    const float* wbeta1 = (const float*)d_in[12];
    const float* bn_g = (const float*)d_in[13]; const float* bn_b = (const float*)d_in[14];
    const float* bn_m = (const float*)d_in[15]; const float* bn_v = (const float*)d_in[16];
    const float* wq2 = (const float*)d_in[17]; const float* bq2 = (const float*)d_in[18];
    const float* wk2 = (const float*)d_in[19]; const float* bk2 = (const float*)d_in[20];
    const float* wv2 = (const float*)d_in[21]; const float* bv2 = (const float*)d_in[22];
    const float* ws2 = (const float*)d_in[23]; const float* bs2 = (const float*)d_in[24];
    const float* wbeta2 = (const float*)d_in[25];
    float* outp = (float*)d_out;

    char* p = (char*)d_ws;
    auto alloc = [&](size_t bytes) { char* q = p; p += (bytes + 255) & ~(size_t)255; return q; };
    float* k1   = (float*)alloc(sizeof(float)*(size_t)NN0*HC1);
    float* v1   = (float*)alloc(sizeof(float)*(size_t)NN0*HC1);
    float* q1   = (float*)alloc(sizeof(float)*(size_t)NN1*HC1);  // later reused as attention out
    float* xr1  = (float*)alloc(sizeof(float)*(size_t)NN1*HC1);
    float* h    = (float*)alloc(sizeof(float)*(size_t)NN1*HC1);
    float* alpha1 = (float*)alloc(sizeof(float)*(size_t)NE1*2);
    float* k2   = (float*)alloc(sizeof(float)*(size_t)NN1*HC2);
    float* v2   = (float*)alloc(sizeof(float)*(size_t)NN1*HC2);
    float* q2   = (float*)alloc(sizeof(float)*(size_t)NB*HC2);   // later reused as attention out
    float* xr2  = (float*)alloc(sizeof(float)*(size_t)NB*HC2);
    float* alpha2 = (float*)alloc(sizeof(float)*(size_t)NE2);
    int* cnt1   = (int*)alloc(sizeof(int)*NN1);
    int* offs1  = (int*)alloc(sizeof(int)*(NN1+1));
    int* cur1   = (int*)alloc(sizeof(int)*NN1);
    int* elist1 = (int*)alloc(sizeof(int)*NE1);
    int* cnt2   = (int*)alloc(sizeof(int)*NB);
    int* offs2  = (int*)alloc(sizeof(int)*(NB+1));
    int* cur2   = (int*)alloc(sizeof(int)*NB);
    int* elist2 = (int*)alloc(sizeof(int)*NE2);
    (void)ws_size; (void)in_sizes; (void)n_in; (void)out_size;

    for (int r = 0; r < RR; ++r) {
        const int* nid  = n_ids + (size_t)r*NN0;
        const int* src1 = ei1 + (size_t)r*2*NE1;
        const int* dst1 = src1 + NE1;
        const int* src2 = ei2 + (size_t)r*2*NE2;
        const int* dst2 = src2 + NE2;

        // ---- layer 1 CSR ----
        hipMemsetAsync(cnt1, 0, sizeof(int)*NN1, stream);
        hist_k<<<512, 256, 0, stream>>>(dst1, NE1, cnt1);
        exscan_k<<<1, 256, 0, stream>>>(cnt1, NN1, offs1, cur1);
        scatter_k<<<512, 256, 0, stream>>>(dst1, NE1, cur1, elist1);

        // ---- layer 1 projections (fused gather) ----
        gemm2k<FIN, HC1, 16><<<NN0/16, 256, 0, stream>>>(
            features, FIN, nid, NN0,
            wk1 + (size_t)r*FIN*HC1, bk1 + r*HC1, k1,
            wv1 + (size_t)r*FIN*HC1, bv1 + r*HC1, v1);
        gemm2k<FIN, HC1, 16><<<NN1/16, 256, 0, stream>>>(
            features, FIN, nid, NN1,
            wq1 + (size_t)r*FIN*HC1, bq1 + r*HC1, q1,
            ws1 + (size_t)r*FIN*HC1, bs1 + r*HC1, xr1);

        // ---- layer 1 attention ----
        edge_alpha<HC1, 2><<<4096, 256, 0, stream>>>(src1, dst1, NE1, q1, k1, alpha1);
        agg_l1<<<NN1, 64, 0, stream>>>(offs1, elist1, src1, alpha1, v1, q1);
        beta_bn_elu<<<NN1, 64, 0, stream>>>(q1, xr1, wbeta1 + (size_t)r*3*HC1,
            bn_g + (size_t)r*HC1, bn_b + (size_t)r*HC1,
            bn_m + (size_t)r*HC1, bn_v + (size_t)r*HC1, h);

        // ---- layer 2 CSR ----
        hipMemsetAsync(cnt2, 0, sizeof(int)*NB, stream);
        hist_k<<<256, 256, 0, stream>>>(dst2, NE2, cnt2);
        exscan_k<<<1, 256, 0, stream>>>(cnt2, NB, offs2, cur2);
        scatter_k<<<256, 256, 0, stream>>>(dst2, NE2, cur2, elist2);

        // ---- layer 2 projections ----
        gemm2k<HC1, HC2, 16><<<NN1/16, 256, 0, stream>>>(
            h, HC1, nullptr, NN1,
            wk2 + (size_t)r*HC1*HC2, bk2 + r*HC2, k2,
            wv2 + (size_t)r*HC1*HC2, bv2 + r*HC2, v2);
        gemm2k<HC1, HC2, 16><<<NB/16, 256, 0, stream>>>(
            h, HC1, nullptr, NB,
            wq2 + (size_t)r*HC1*HC2, bq2 + r*HC2, q2,
            ws2 + (size_t)r*HC1*HC2, bs2 + r*HC2, xr2);

        // ---- layer 2 attention + output ----
        edge_alpha<HC2, 1><<<1024, 256, 0, stream>>>(src2, dst2, NE2, q2, k2, alpha2);
        agg_l2<<<NB, 64, 0, stream>>>(offs2, elist2, src2, alpha2, v2, q2);
        beta_out<<<NB, 64, 0, stream>>>(q2, xr2, wbeta2 + (size_t)r*3*HC2, outp, r*HC2);
    }
}

// Round 2
// 1891.155 us; speedup vs baseline: 1.0331x; 1.0331x over previous
//
#include <hip/hip_runtime.h>
#include <math.h>

#define RR 3
#define NTOT 100000
#define NN0 80000
#define NN1 20000
#define NB 4096
#define NE1 300000
#define NE2 65536
#define FIN 128
#define HC1 256   // layer1: 2 heads x 128
#define HC2 128   // layer2: 1 head x 128

typedef __attribute__((ext_vector_type(8))) short bf16x8;
typedef __attribute__((ext_vector_type(4))) short s16x4;
typedef __attribute__((ext_vector_type(4))) float f32x4;

__device__ __forceinline__ float wave_red_sum(float v) {
    #pragma unroll
    for (int off = 32; off >= 1; off >>= 1) v += __shfl_xor(v, off, 64);
    return v;
}

__device__ __forceinline__ short f2bf(float x) {
    union { float f; unsigned u; } c; c.f = x;
    unsigned r = c.u + 0x7fffu + ((c.u >> 16) & 1u);
    return (short)(r >> 16);
}

// ---------- convert features f32 -> bf16 ----------
__global__ void __launch_bounds__(256)
fcvt_k(const float* __restrict__ f, short* __restrict__ o, int n4) {
    int i = blockIdx.x * 256 + threadIdx.x;
    if (i < n4) {
        float4 v = *(const float4*)(f + (size_t)i * 4);
        s16x4 s = { f2bf(v.x), f2bf(v.y), f2bf(v.z), f2bf(v.w) };
        *(s16x4*)(o + (size_t)i * 4) = s;
    }
}

// ---------- convert+transpose 4 weight mats per replica: W[K][N] f32 -> Wt[N][K] bf16 ----------
__global__ void __launch_bounds__(256)
wcvt4_k(const float* __restrict__ W0, const float* __restrict__ W1,
        const float* __restrict__ W2, const float* __restrict__ W3,
        short* __restrict__ Wt, int K, int N) {
    const int m = blockIdx.y, r = blockIdx.z;
    const float* W = (m == 0 ? W0 : m == 1 ? W1 : m == 2 ? W2 : W3) + (size_t)r * K * N;
    short* o = Wt + ((size_t)(r * 4 + m)) * K * N;
    for (int i = blockIdx.x * 256 + threadIdx.x; i < K * N; i += gridDim.x * 256) {
        int n = i / K, k = i - n * K;
        o[i] = f2bf(W[(size_t)k * N + n]);   // coalesced write, strided read (L2-resident)
    }
}

// ---------- MFMA GEMM: out0 = x@W0+b0, out1 = x@W1+b1, optional row gather ----------
// xbf: bf16 [*, ldx]; Wt*: bf16 [N][K] (pre-transposed); out*: f32 [M][N]
template<int K, int N>
__global__ void __launch_bounds__(256)
gemm2m(const short* __restrict__ xbf, int ldx, const int* __restrict__ gidx, int M,
       const short* __restrict__ Wt0, const float* __restrict__ b0, float* __restrict__ out0,
       const short* __restrict__ Wt1, const float* __restrict__ b1, float* __restrict__ out1)
{
    constexpr int NT = N / 16;   // 16x16 n-tiles
    constexpr int KS = K / 32;   // k-steps
    const int lane = threadIdx.x & 63;
    const int wid  = threadIdx.x >> 6;
    const int rowbase = (blockIdx.x * 4 + wid) * 16;

    // A fragment: lane holds row (lane&15), k = 8*(lane>>4)+j (contiguous 16B)
    const int arow = rowbase + (lane & 15);
    int srow = 0;
    if (arow < M) srow = gidx ? gidx[arow] : arow;
    const short* ap = xbf + (size_t)srow * ldx + ((lane >> 4) * 8);

    // B fragment from Wt[n][k]: lane holds col (lane&15), k = 8*(lane>>4)+j
    const int bn = lane & 15;
    const int bk = (lane >> 4) * 8;

    f32x4 acc0[NT], acc1[NT];
    #pragma unroll
    for (int nt = 0; nt < NT; ++nt) { acc0[nt] = (f32x4)(0.0f); acc1[nt] = (f32x4)(0.0f); }

    for (int ks = 0; ks < KS; ++ks) {
        bf16x8 a = *(const bf16x8*)(ap + ks * 32);
        const short* b0p = Wt0 + (size_t)bn * K + ks * 32 + bk;
        const short* b1p = Wt1 + (size_t)bn * K + ks * 32 + bk;
        #pragma unroll
        for (int nt = 0; nt < NT; ++nt) {
            bf16x8 bv0 = *(const bf16x8*)(b0p + (size_t)nt * 16 * K);
            acc0[nt] = __builtin_amdgcn_mfma_f32_16x16x32_bf16(a, bv0, acc0[nt], 0, 0, 0);
            bf16x8 bv1 = *(const bf16x8*)(b1p + (size_t)nt * 16 * K);
            acc1[nt] = __builtin_amdgcn_mfma_f32_16x16x32_bf16(a, bv1, acc1[nt], 0, 0, 0);
        }
    }

    // C/D: col = lane&15, row = 4*(lane>>4)+reg  [verified layout]
    const int crow0 = rowbase + (lane >> 4) * 4;
    const int ccol = lane & 15;
    #pragma unroll
    for (int nt = 0; nt < NT; ++nt) {
        const float bb0 = b0[nt * 16 + ccol];
        const float bb1 = b1[nt * 16 + ccol];
        #pragma unroll
        for (int rg = 0; rg < 4; ++rg) {
            int rr = crow0 + rg;
            if (rr < M) {
                out0[(size_t)rr * N + nt * 16 + ccol] = acc0[nt][rg] + bb0;
                out1[(size_t)rr * N + nt * 16 + ccol] = acc1[nt][rg] + bb1;
            }
        }
    }
}

// ---------- per-edge attention logits ----------
template<int HC, int H>
__global__ void __launch_bounds__(256)
edge_alpha(const int* __restrict__ src, const int* __restrict__ dst, int E,
           const float* __restrict__ q, const float* __restrict__ k,
           float* __restrict__ alpha)
{
    constexpr int EPL = HC / 64;
    constexpr int C = HC / H;
    constexpr int GL = 64 / H;
    const int lane = threadIdx.x & 63;
    const int wid = (blockIdx.x * blockDim.x + threadIdx.x) >> 6;
    const int nw = (gridDim.x * blockDim.x) >> 6;
    const float scale = rsqrtf((float)C);
    for (int e = wid; e < E; e += nw) {
        const int s = src[e], d = dst[e];
        const float* qp = q + (size_t)d * HC + lane * EPL;
        const float* kp = k + (size_t)s * HC + lane * EPL;
        float part;
        if constexpr (EPL == 4) {
            float4 qv = *(const float4*)qp, kv = *(const float4*)kp;
            part = qv.x*kv.x + qv.y*kv.y + qv.z*kv.z + qv.w*kv.w;
        } else {
            float2 qv = *(const float2*)qp, kv = *(const float2*)kp;
            part = qv.x*kv.x + qv.y*kv.y;
        }
        #pragma unroll
        for (int off = GL/2; off >= 1; off >>= 1) part += __shfl_xor(part, off, 64);
        if ((lane & (GL-1)) == 0)
            alpha[(size_t)e*H + lane/GL] = part * scale;
    }
}

// ---------- CSR helpers ----------
__global__ void hist_k(const int* __restrict__ dst, int E, int* __restrict__ cnt) {
    for (int e = blockIdx.x*blockDim.x + threadIdx.x; e < E; e += gridDim.x*blockDim.x)
        atomicAdd(&cnt[dst[e]], 1);
}
__global__ void __launch_bounds__(256)
exscan_k(const int* __restrict__ cnt, int n, int* __restrict__ offs, int* __restrict__ cur) {
    __shared__ int ps[256];
    const int tid = threadIdx.x;
    const int chunk = (n + 255) / 256;
    const int lo = tid * chunk;
    const int hi = min(lo + chunk, n);
    int s = 0;
    for (int i = lo; i < hi; ++i) s += cnt[i];
    ps[tid] = s;
    __syncthreads();
    for (int off = 1; off < 256; off <<= 1) {
        int v = (tid >= off) ? ps[tid - off] : 0;
        __syncthreads();
        ps[tid] += v;
        __syncthreads();
    }
    int run = (tid == 0) ? 0 : ps[tid - 1];
    for (int i = lo; i < hi; ++i) { offs[i] = run; cur[i] = run; run += cnt[i]; }
    if (tid == 255) offs[n] = ps[255];
}
__global__ void scatter_k(const int* __restrict__ dst, int E, int* __restrict__ cur, int* __restrict__ elist) {
    for (int e = blockIdx.x*blockDim.x + threadIdx.x; e < E; e += gridDim.x*blockDim.x) {
        int pos = atomicAdd(&cur[dst[e]], 1);
        elist[pos] = e;
    }
}

// ---------- per-node softmax-aggregate (layer1: H=2, C=128) ----------
__global__ void __launch_bounds__(64)
agg_l1(const int* __restrict__ offs, const int* __restrict__ elist,
       const int* __restrict__ src, const float* __restrict__ alpha,
       const float* __restrict__ v, float* __restrict__ out)
{
    const int n = blockIdx.x;
    const int lane = threadIdx.x;
    const int c0 = lane * 4;
    const int hd = c0 >> 7;
    const int lo = offs[n], hi = offs[n+1];
    float m = -INFINITY;
    for (int i = lo; i < hi; ++i)
        m = fmaxf(m, alpha[(size_t)elist[i]*2 + hd]);
    float s = 0.f;
    float a0=0.f, a1=0.f, a2=0.f, a3=0.f;
    for (int i = lo; i < hi; ++i) {
        int e = elist[i];
        float p = __expf(alpha[(size_t)e*2 + hd] - m);
        s += p;
        const float4 vv = *(const float4*)(v + (size_t)src[e]*HC1 + c0);
        a0 = fmaf(p, vv.x, a0); a1 = fmaf(p, vv.y, a1);
        a2 = fmaf(p, vv.z, a2); a3 = fmaf(p, vv.w, a3);
    }
    const float inv = (s > 0.f) ? 1.f/s : 0.f;
    float4 o = { a0*inv, a1*inv, a2*inv, a3*inv };
    *(float4*)(out + (size_t)n*HC1 + c0) = o;
}

// ---------- per-node softmax-aggregate (layer2: H=1, C=128) ----------
__global__ void __launch_bounds__(64)
agg_l2(const int* __restrict__ offs, const int* __restrict__ elist,
       const int* __restrict__ src, const float* __restrict__ alpha,
       const float* __restrict__ v, float* __restrict__ out)
{
    const int n = blockIdx.x;
    const int lane = threadIdx.x;
    const int c0 = lane * 2;
    const int lo = offs[n], hi = offs[n+1];
    float m = -INFINITY;
    for (int i = lo; i < hi; ++i)
        m = fmaxf(m, alpha[elist[i]]);
    float s = 0.f; float a0=0.f, a1=0.f;
    for (int i = lo; i < hi; ++i) {
        int e = elist[i];
        float p = __expf(alpha[e] - m);
        s += p;
        const float2 vv = *(const float2*)(v + (size_t)src[e]*HC2 + c0);
        a0 = fmaf(p, vv.x, a0); a1 = fmaf(p, vv.y, a1);
    }
    const float inv = (s > 0.f) ? 1.f/s : 0.f;
    float2 o = { a0*inv, a1*inv };
    *(float2*)(out + (size_t)n*HC2 + c0) = o;
}

// ---------- layer1 epilogue: beta gate + BN(eval) + ELU -> bf16 h ----------
__global__ void __launch_bounds__(64)
beta_bn_elu(const float* __restrict__ att, const float* __restrict__ xr,
            const float* __restrict__ wb,
            const float* __restrict__ g, const float* __restrict__ bb,
            const float* __restrict__ mean, const float* __restrict__ var,
            short* __restrict__ hb)
{
    const int n = blockIdx.x;
    const int lane = threadIdx.x;
    const int c0 = lane * 4;
    float4 o4 = *(const float4*)(att + (size_t)n*HC1 + c0);
    float4 x4 = *(const float4*)(xr + (size_t)n*HC1 + c0);
    float oo[4] = {o4.x,o4.y,o4.z,o4.w};
    float xx[4] = {x4.x,x4.y,x4.z,x4.w};
    float d = 0.f;
    #pragma unroll
    for (int j = 0; j < 4; ++j) {
        int c = c0 + j;
        d += oo[j]*wb[c] + xx[j]*wb[HC1 + c] + (oo[j]-xx[j])*wb[2*HC1 + c];
    }
    d = wave_red_sum(d);
    const float beta = 1.f / (1.f + __expf(-d));
    s16x4 hv4;
    #pragma unroll
    for (int j = 0; j < 4; ++j) {
        int c = c0 + j;
        float hv = beta*xx[j] + (1.f-beta)*oo[j];
        hv = (hv - mean[c]) * rsqrtf(var[c] + 1e-5f) * g[c] + bb[c];
        hv = hv > 0.f ? hv : expm1f(hv);
        hv4[j] = f2bf(hv);
    }
    *(s16x4*)(hb + (size_t)n*HC1 + c0) = hv4;
}

// ---------- layer2 epilogue: beta gate + strided output write ----------
__global__ void __launch_bounds__(64)
beta_out(const float* __restrict__ att, const float* __restrict__ xr,
         const float* __restrict__ wb, float* __restrict__ outp, int colofs)
{
    const int n = blockIdx.x;
    const int lane = threadIdx.x;
    const int c0 = lane * 2;
    float2 o = *(const float2*)(att + (size_t)n*HC2 + c0);
    float2 x = *(const float2*)(xr + (size_t)n*HC2 + c0);
    float d = o.x*wb[c0] + o.y*wb[c0+1]
            + x.x*wb[HC2+c0] + x.y*wb[HC2+c0+1]
            + (o.x-x.x)*wb[2*HC2+c0] + (o.y-x.y)*wb[2*HC2+c0+1];
    d = wave_red_sum(d);
    const float beta = 1.f/(1.f+__expf(-d));
    outp[(size_t)n*(RR*HC2) + colofs + c0]     = beta*x.x + (1.f-beta)*o.x;
    outp[(size_t)n*(RR*HC2) + colofs + c0 + 1] = beta*x.y + (1.f-beta)*o.y;
}

extern "C" void kernel_launch(void* const* d_in, const int* in_sizes, int n_in,
                              void* d_out, int out_size, void* d_ws, size_t ws_size,
                              hipStream_t stream)
{
    const float* features = (const float*)d_in[0];
    const int*   n_ids    = (const int*)d_in[1];
    const int*   ei1      = (const int*)d_in[2];
    const int*   ei2      = (const int*)d_in[3];
    const float* wq1 = (const float*)d_in[4];  const float* bq1 = (const float*)d_in[5];
    const float* wk1 = (const float*)d_in[6];  const float* bk1 = (const float*)d_in[7];
    const float* wv1 = (const float*)d_in[8];  const float* bv1 = (const float*)d_in[9];
    const float* ws1 = (const float*)d_in[10]; const float* bs1 = (const float*)d_in[11];
    const float* wbeta1 = (const float*)d_in[12];
    const float* bn_g = (const float*)d_in[13]; const float* bn_b = (const float*)d_in[14];
    const float* bn_m = (const float*)d_in[15]; const float* bn_v = (const float*)d_in[16];
    const float* wq2 = (const float*)d_in[17]; const float* bq2 = (const float*)d_in[18];
    const float* wk2 = (const float*)d_in[19]; const float* bk2 = (const float*)d_in[20];
    const float* wv2 = (const float*)d_in[21]; const float* bv2 = (const float*)d_in[22];
    const float* ws2 = (const float*)d_in[23]; const float* bs2 = (const float*)d_in[24];
    const float* wbeta2 = (const float*)d_in[25];
    float* outp = (float*)d_out;

    char* p = (char*)d_ws;
    auto alloc = [&](size_t bytes) { char* q = p; p += (bytes + 255) & ~(size_t)255; return q; };
    // persistent (per-replica serially reused) buffers
    float* k1   = (float*)alloc(sizeof(float)*(size_t)NN0*HC1);   // 81.92 MB
    float* v1   = (float*)alloc(sizeof(float)*(size_t)NN0*HC1);   // 81.92 MB
    float* q1   = (float*)alloc(sizeof(float)*(size_t)NN1*HC1);   // also attention out
    float* xr1  = (float*)alloc(sizeof(float)*(size_t)NN1*HC1);
    float* alpha1 = (float*)alloc(sizeof(float)*(size_t)NE1*2);
    short* xbf  = (short*)alloc(sizeof(short)*(size_t)NTOT*FIN);  // 25.6 MB
    short* wt1  = (short*)alloc(sizeof(short)*(size_t)RR*4*FIN*HC1);
    short* wt2  = (short*)alloc(sizeof(short)*(size_t)RR*4*HC1*HC2);
    int* cnt1   = (int*)alloc(sizeof(int)*NN1);
    int* offs1  = (int*)alloc(sizeof(int)*(NN1+1));
    int* cur1   = (int*)alloc(sizeof(int)*NN1);
    int* elist1 = (int*)alloc(sizeof(int)*NE1);
    int* cnt2   = (int*)alloc(sizeof(int)*NB);
    int* offs2  = (int*)alloc(sizeof(int)*(NB+1));
    int* cur2   = (int*)alloc(sizeof(int)*NB);
    int* elist2 = (int*)alloc(sizeof(int)*NE2);
    // stream-ordered aliases:
    // hbf lives in k1's region (k1 dead after edge_alpha; hbf written by beta_bn_elu, read
    // by layer2 gemms, dead before next replica's kv gemm rewrites k1).
    short* hbf = (short*)k1;                                      // 10.24 MB used
    // layer2 f32 buffers live in v1's region (v1 dead after agg_l1; these are written by
    // layer2 gemms and consumed by beta_out, all before next replica rewrites v1).
    char* vp = (char*)v1;
    auto valloc = [&](size_t bytes) { char* q = vp; vp += (bytes + 255) & ~(size_t)255; return q; };
    float* k2   = (float*)valloc(sizeof(float)*(size_t)NN1*HC2);
    float* v2   = (float*)valloc(sizeof(float)*(size_t)NN1*HC2);
    float* q2   = (float*)valloc(sizeof(float)*(size_t)NB*HC2);
    float* xr2  = (float*)valloc(sizeof(float)*(size_t)NB*HC2);
    float* alpha2 = (float*)valloc(sizeof(float)*(size_t)NE2);
    (void)ws_size; (void)in_sizes; (void)n_in; (void)out_size;

    // ---- prologue: dtype conversions (once per launch) ----
    fcvt_k<<<(NTOT*FIN/4 + 255)/256, 256, 0, stream>>>(features, xbf, NTOT*FIN/4);
    {
        dim3 g1(32, 4, RR);
        wcvt4_k<<<g1, 256, 0, stream>>>(wq1, wk1, wv1, ws1, wt1, FIN, HC1);
        dim3 g2(32, 4, RR);
        wcvt4_k<<<g2, 256, 0, stream>>>(wq2, wk2, wv2, ws2, wt2, HC1, HC2);
    }
    const size_t WSZ = (size_t)FIN*HC1;   // 32768 elems, same for both layers

    for (int r = 0; r < RR; ++r) {
        const int* nid  = n_ids + (size_t)r*NN0;
        const int* src1 = ei1 + (size_t)r*2*NE1;
        const int* dst1 = src1 + NE1;
        const int* src2 = ei2 + (size_t)r*2*NE2;
        const int* dst2 = src2 + NE2;
        const short* wtq1 = wt1 + ((size_t)r*4 + 0)*WSZ;
        const short* wtk1 = wt1 + ((size_t)r*4 + 1)*WSZ;
        const short* wtv1 = wt1 + ((size_t)r*4 + 2)*WSZ;
        const short* wts1 = wt1 + ((size_t)r*4 + 3)*WSZ;
        const short* wtq2 = wt2 + ((size_t)r*4 + 0)*WSZ;
        const short* wtk2 = wt2 + ((size_t)r*4 + 1)*WSZ;
        const short* wtv2 = wt2 + ((size_t)r*4 + 2)*WSZ;
        const short* wts2 = wt2 + ((size_t)r*4 + 3)*WSZ;

        // ---- layer 1 CSR ----
        hipMemsetAsync(cnt1, 0, sizeof(int)*NN1, stream);
        hist_k<<<512, 256, 0, stream>>>(dst1, NE1, cnt1);
        exscan_k<<<1, 256, 0, stream>>>(cnt1, NN1, offs1, cur1);
        scatter_k<<<512, 256, 0, stream>>>(dst1, NE1, cur1, elist1);

        // ---- layer 1 projections (MFMA, fused gather) ----
        gemm2m<FIN, HC1><<<NN0/64, 256, 0, stream>>>(
            xbf, FIN, nid, NN0, wtk1, bk1 + r*HC1, k1, wtv1, bv1 + r*HC1, v1);
        gemm2m<FIN, HC1><<<(NN1+63)/64, 256, 0, stream>>>(
            xbf, FIN, nid, NN1, wtq1, bq1 + r*HC1, q1, wts1, bs1 + r*HC1, xr1);

        // ---- layer 1 attention ----
        edge_alpha<HC1, 2><<<4096, 256, 0, stream>>>(src1, dst1, NE1, q1, k1, alpha1);
        agg_l1<<<NN1, 64, 0, stream>>>(offs1, elist1, src1, alpha1, v1, q1);
        beta_bn_elu<<<NN1, 64, 0, stream>>>(q1, xr1, wbeta1 + (size_t)r*3*HC1,
            bn_g + (size_t)r*HC1, bn_b + (size_t)r*HC1,
            bn_m + (size_t)r*HC1, bn_v + (size_t)r*HC1, hbf);

        // ---- layer 2 CSR ----
        hipMemsetAsync(cnt2, 0, sizeof(int)*NB, stream);
        hist_k<<<256, 256, 0, stream>>>(dst2, NE2, cnt2);
        exscan_k<<<1, 256, 0, stream>>>(cnt2, NB, offs2, cur2);
        scatter_k<<<256, 256, 0, stream>>>(dst2, NE2, cur2, elist2);

        // ---- layer 2 projections (MFMA) ----
        gemm2m<HC1, HC2><<<(NN1+63)/64, 256, 0, stream>>>(
            hbf, HC1, nullptr, NN1, wtk2, bk2 + r*HC2, k2, wtv2, bv2 + r*HC2, v2);
        gemm2m<HC1, HC2><<<NB/64, 256, 0, stream>>>(
            hbf, HC1, nullptr, NB, wtq2, bq2 + r*HC2, q2, wts2, bs2 + r*HC2, xr2);

        // ---- layer 2 attention + output ----
        edge_alpha<HC2, 1><<<1024, 256, 0, stream>>>(src2, dst2, NE2, q2, k2, alpha2);
        agg_l2<<<NB, 64, 0, stream>>>(offs2, elist2, src2, alpha2, v2, q2);
        beta_out<<<NB, 64, 0, stream>>>(q2, xr2, wbeta2 + (size_t)r*3*HC2, outp, r*HC2);
    }
}

// Round 3
// 1600.330 us; speedup vs baseline: 1.2208x; 1.1817x over previous
//
#include <hip/hip_runtime.h>
#include <math.h>

#define RR 3
#define NTOT 100000
#define NN0 80000
#define NN1 20000
#define NB 4096
#define NE1 300000
#define NE2 65536
#define FIN 128
#define HC1 256   // layer1: 2 heads x 128
#define HC2 128   // layer2: 1 head x 128

typedef __attribute__((ext_vector_type(8))) short bf16x8;
typedef __attribute__((ext_vector_type(4))) short s16x4;
typedef __attribute__((ext_vector_type(2))) short s16x2;
typedef __attribute__((ext_vector_type(4))) float f32x4;

__device__ __forceinline__ float wave_red_sum(float v) {
    #pragma unroll
    for (int off = 32; off >= 1; off >>= 1) v += __shfl_xor(v, off, 64);
    return v;
}

__device__ __forceinline__ short f2bf(float x) {
    union { float f; unsigned u; } c; c.f = x;
    unsigned r = c.u + 0x7fffu + ((c.u >> 16) & 1u);
    return (short)(r >> 16);
}
__device__ __forceinline__ float bf2f(short s) {
    union { unsigned u; float f; } c; c.u = ((unsigned)(unsigned short)s) << 16;
    return c.f;
}

// generic 4-elem and 2-elem row loads (f32 or bf16)
__device__ __forceinline__ float4 ld4(const float* p) { return *(const float4*)p; }
__device__ __forceinline__ float4 ld4(const short* p) {
    s16x4 v = *(const s16x4*)p;
    float4 r = { bf2f(v[0]), bf2f(v[1]), bf2f(v[2]), bf2f(v[3]) };
    return r;
}
__device__ __forceinline__ float2 ld2(const float* p) { return *(const float2*)p; }
__device__ __forceinline__ float2 ld2(const short* p) {
    s16x2 v = *(const s16x2*)p;
    float2 r = { bf2f(v[0]), bf2f(v[1]) };
    return r;
}

// ---------- convert features f32 -> bf16 ----------
__global__ void __launch_bounds__(256)
fcvt_k(const float* __restrict__ f, short* __restrict__ o, int n4) {
    int i = blockIdx.x * 256 + threadIdx.x;
    if (i < n4) {
        float4 v = *(const float4*)(f + (size_t)i * 4);
        s16x4 s = { f2bf(v.x), f2bf(v.y), f2bf(v.z), f2bf(v.w) };
        *(s16x4*)(o + (size_t)i * 4) = s;
    }
}

// ---------- pack 4 weight mats per replica into MFMA B-fragment order ----------
// W[K][N] f32 -> P[((nt*KS+ks)*64+lane)*8+j] = bf16(W[ks*32+(lane>>4)*8+j][nt*16+(lane&15)])
template<int K, int N>
__global__ void __launch_bounds__(256)
wpack_k(const float* __restrict__ W0, const float* __restrict__ W1,
        const float* __restrict__ W2, const float* __restrict__ W3,
        short* __restrict__ P) {
    constexpr int KS = K / 32;
    const int m = blockIdx.y, r = blockIdx.z;
    const float* W = (m == 0 ? W0 : m == 1 ? W1 : m == 2 ? W2 : W3) + (size_t)r * K * N;
    short* o = P + ((size_t)(r * 4 + m)) * K * N;
    for (int i = blockIdx.x * 256 + threadIdx.x; i < K * N; i += gridDim.x * 256) {
        int j = i & 7, lane = (i >> 3) & 63, f = i >> 9;
        int ks = f % KS, nt = f / KS;
        int k = ks * 32 + (lane >> 4) * 8 + j;
        int n = nt * 16 + (lane & 15);
        o[i] = f2bf(W[(size_t)k * N + n]);
    }
}

// ---------- MFMA GEMM: out0 = x@W0+b0, out1 = x@W1+b1, optional row gather ----------
// xbf: bf16 [*, ldx]; P*: packed bf16 fragments; out*: f32 or bf16 [M][N]
template<int K, int N, typename OT0, typename OT1>
__global__ void __launch_bounds__(256)
gemm2m(const short* __restrict__ xbf, int ldx, const int* __restrict__ gidx, int M,
       const short* __restrict__ P0, const float* __restrict__ b0, OT0* __restrict__ out0,
       const short* __restrict__ P1, const float* __restrict__ b1, OT1* __restrict__ out1)
{
    constexpr int NT = N / 16;   // 16x16 n-tiles
    constexpr int KS = K / 32;   // k-steps
    const int lane = threadIdx.x & 63;
    const int wid  = threadIdx.x >> 6;
    const int rowbase = (blockIdx.x * 4 + wid) * 16;

    // A fragment: lane holds row (lane&15), k = 8*(lane>>4)+j (contiguous 16B)
    const int arow = rowbase + (lane & 15);
    int srow = 0;
    if (arow < M) srow = gidx ? gidx[arow] : arow;
    const short* ap = xbf + (size_t)srow * ldx + ((lane >> 4) * 8);
    const int fb = lane * 8;   // fragment base within packed 512-elem chunk

    f32x4 acc0[NT], acc1[NT];
    #pragma unroll
    for (int nt = 0; nt < NT; ++nt) { acc0[nt] = (f32x4)(0.0f); acc1[nt] = (f32x4)(0.0f); }

    for (int ks = 0; ks < KS; ++ks) {
        bf16x8 a = *(const bf16x8*)(ap + ks * 32);
        #pragma unroll
        for (int nt = 0; nt < NT; ++nt) {
            const int off = ((nt * KS + ks) << 9) + fb;   // coalesced 1KB wave load
            bf16x8 bv0 = *(const bf16x8*)(P0 + off);
            acc0[nt] = __builtin_amdgcn_mfma_f32_16x16x32_bf16(a, bv0, acc0[nt], 0, 0, 0);
            bf16x8 bv1 = *(const bf16x8*)(P1 + off);
            acc1[nt] = __builtin_amdgcn_mfma_f32_16x16x32_bf16(a, bv1, acc1[nt], 0, 0, 0);
        }
    }

    // C/D: col = lane&15, row = 4*(lane>>4)+reg  [verified layout]
    const int crow0 = rowbase + (lane >> 4) * 4;
    const int ccol = lane & 15;
    #pragma unroll
    for (int nt = 0; nt < NT; ++nt) {
        const float bb0 = b0[nt * 16 + ccol];
        const float bb1 = b1[nt * 16 + ccol];
        #pragma unroll
        for (int rg = 0; rg < 4; ++rg) {
            int rr = crow0 + rg;
            if (rr < M) {
                float v0 = acc0[nt][rg] + bb0;
                float v1 = acc1[nt][rg] + bb1;
                if constexpr (sizeof(OT0) == 2) out0[(size_t)rr * N + nt * 16 + ccol] = f2bf(v0);
                else                            out0[(size_t)rr * N + nt * 16 + ccol] = v0;
                if constexpr (sizeof(OT1) == 2) out1[(size_t)rr * N + nt * 16 + ccol] = f2bf(v1);
                else                            out1[(size_t)rr * N + nt * 16 + ccol] = v1;
            }
        }
    }
}

// ---------- per-edge attention logits ----------
template<int HC, int H, typename QT, typename KT>
__global__ void __launch_bounds__(256)
edge_alpha(const int* __restrict__ src, const int* __restrict__ dst, int E,
           const QT* __restrict__ q, const KT* __restrict__ k,
           float* __restrict__ alpha)
{
    constexpr int EPL = HC / 64;
    constexpr int C = HC / H;
    constexpr int GL = 64 / H;
    const int lane = threadIdx.x & 63;
    const int wid = (blockIdx.x * blockDim.x + threadIdx.x) >> 6;
    const int nw = (gridDim.x * blockDim.x) >> 6;
    const float scale = rsqrtf((float)C);
    for (int e = wid; e < E; e += nw) {
        const int s = src[e], d = dst[e];
        const QT* qp = q + (size_t)d * HC + lane * EPL;
        const KT* kp = k + (size_t)s * HC + lane * EPL;
        float part;
        if constexpr (EPL == 4) {
            float4 qv = ld4(qp), kv = ld4(kp);
            part = qv.x*kv.x + qv.y*kv.y + qv.z*kv.z + qv.w*kv.w;
        } else {
            float2 qv = ld2(qp), kv = ld2(kp);
            part = qv.x*kv.x + qv.y*kv.y;
        }
        #pragma unroll
        for (int off = GL/2; off >= 1; off >>= 1) part += __shfl_xor(part, off, 64);
        if ((lane & (GL-1)) == 0)
            alpha[(size_t)e*H + lane/GL] = part * scale;
    }
}

// ---------- CSR helpers ----------
__global__ void hist_k(const int* __restrict__ dst, int E, int* __restrict__ cnt) {
    for (int e = blockIdx.x*blockDim.x + threadIdx.x; e < E; e += gridDim.x*blockDim.x)
        atomicAdd(&cnt[dst[e]], 1);
}
__global__ void __launch_bounds__(256)
exscan_k(const int* __restrict__ cnt, int n, int* __restrict__ offs, int* __restrict__ cur) {
    __shared__ int ps[256];
    const int tid = threadIdx.x;
    const int chunk = (n + 255) / 256;
    const int lo = tid * chunk;
    const int hi = min(lo + chunk, n);
    int s = 0;
    for (int i = lo; i < hi; ++i) s += cnt[i];
    ps[tid] = s;
    __syncthreads();
    for (int off = 1; off < 256; off <<= 1) {
        int v = (tid >= off) ? ps[tid - off] : 0;
        __syncthreads();
        ps[tid] += v;
        __syncthreads();
    }
    int run = (tid == 0) ? 0 : ps[tid - 1];
    for (int i = lo; i < hi; ++i) { offs[i] = run; cur[i] = run; run += cnt[i]; }
    if (tid == 255) offs[n] = ps[255];
}
__global__ void scatter_k(const int* __restrict__ dst, int E, int* __restrict__ cur, int* __restrict__ elist) {
    for (int e = blockIdx.x*blockDim.x + threadIdx.x; e < E; e += gridDim.x*blockDim.x) {
        int pos = atomicAdd(&cur[dst[e]], 1);
        elist[pos] = e;
    }
}

// ---------- per-node softmax-aggregate (layer1: H=2, C=128, v bf16) ----------
__global__ void __launch_bounds__(64)
agg_l1(const int* __restrict__ offs, const int* __restrict__ elist,
       const int* __restrict__ src, const float* __restrict__ alpha,
       const short* __restrict__ v, float* __restrict__ out)
{
    const int n = blockIdx.x;
    const int lane = threadIdx.x;
    const int c0 = lane * 4;
    const int hd = c0 >> 7;
    const int lo = offs[n], hi = offs[n+1];
    float m = -INFINITY;
    for (int i = lo; i < hi; ++i)
        m = fmaxf(m, alpha[(size_t)elist[i]*2 + hd]);
    float s = 0.f;
    float a0=0.f, a1=0.f, a2=0.f, a3=0.f;
    for (int i = lo; i < hi; ++i) {
        int e = elist[i];
        float p = __expf(alpha[(size_t)e*2 + hd] - m);
        s += p;
        const float4 vv = ld4(v + (size_t)src[e]*HC1 + c0);
        a0 = fmaf(p, vv.x, a0); a1 = fmaf(p, vv.y, a1);
        a2 = fmaf(p, vv.z, a2); a3 = fmaf(p, vv.w, a3);
    }
    const float inv = (s > 0.f) ? 1.f/s : 0.f;
    float4 o = { a0*inv, a1*inv, a2*inv, a3*inv };
    *(float4*)(out + (size_t)n*HC1 + c0) = o;
}

// ---------- per-node softmax-aggregate (layer2: H=1, C=128, v f32) ----------
__global__ void __launch_bounds__(64)
agg_l2(const int* __restrict__ offs, const int* __restrict__ elist,
       const int* __restrict__ src, const float* __restrict__ alpha,
       const float* __restrict__ v, float* __restrict__ out)
{
    const int n = blockIdx.x;
    const int lane = threadIdx.x;
    const int c0 = lane * 2;
    const int lo = offs[n], hi = offs[n+1];
    float m = -INFINITY;
    for (int i = lo; i < hi; ++i)
        m = fmaxf(m, alpha[elist[i]]);
    float s = 0.f; float a0=0.f, a1=0.f;
    for (int i = lo; i < hi; ++i) {
        int e = elist[i];
        float p = __expf(alpha[e] - m);
        s += p;
        const float2 vv = *(const float2*)(v + (size_t)src[e]*HC2 + c0);
        a0 = fmaf(p, vv.x, a0); a1 = fmaf(p, vv.y, a1);
    }
    const float inv = (s > 0.f) ? 1.f/s : 0.f;
    float2 o = { a0*inv, a1*inv };
    *(float2*)(out + (size_t)n*HC2 + c0) = o;
}

// ---------- layer1 epilogue: beta gate + BN(eval) + ELU -> bf16 h ----------
__global__ void __launch_bounds__(64)
beta_bn_elu(const float* __restrict__ att, const float* __restrict__ xr,
            const float* __restrict__ wb,
            const float* __restrict__ g, const float* __restrict__ bb,
            const float* __restrict__ mean, const float* __restrict__ var,
            short* __restrict__ hb)
{
    const int n = blockIdx.x;
    const int lane = threadIdx.x;
    const int c0 = lane * 4;
    float4 o4 = *(const float4*)(att + (size_t)n*HC1 + c0);
    float4 x4 = *(const float4*)(xr + (size_t)n*HC1 + c0);
    float oo[4] = {o4.x,o4.y,o4.z,o4.w};
    float xx[4] = {x4.x,x4.y,x4.z,x4.w};
    float d = 0.f;
    #pragma unroll
    for (int j = 0; j < 4; ++j) {
        int c = c0 + j;
        d += oo[j]*wb[c] + xx[j]*wb[HC1 + c] + (oo[j]-xx[j])*wb[2*HC1 + c];
    }
    d = wave_red_sum(d);
    const float beta = 1.f / (1.f + __expf(-d));
    s16x4 hv4;
    #pragma unroll
    for (int j = 0; j < 4; ++j) {
        int c = c0 + j;
        float hv = beta*xx[j] + (1.f-beta)*oo[j];
        hv = (hv - mean[c]) * rsqrtf(var[c] + 1e-5f) * g[c] + bb[c];
        hv = hv > 0.f ? hv : expm1f(hv);
        hv4[j] = f2bf(hv);
    }
    *(s16x4*)(hb + (size_t)n*HC1 + c0) = hv4;
}

// ---------- layer2 epilogue: beta gate + strided output write ----------
__global__ void __launch_bounds__(64)
beta_out(const float* __restrict__ att, const float* __restrict__ xr,
         const float* __restrict__ wb, float* __restrict__ outp, int colofs)
{
    const int n = blockIdx.x;
    const int lane = threadIdx.x;
    const int c0 = lane * 2;
    float2 o = *(const float2*)(att + (size_t)n*HC2 + c0);
    float2 x = *(const float2*)(xr + (size_t)n*HC2 + c0);
    float d = o.x*wb[c0] + o.y*wb[c0+1]
            + x.x*wb[HC2+c0] + x.y*wb[HC2+c0+1]
            + (o.x-x.x)*wb[2*HC2+c0] + (o.y-x.y)*wb[2*HC2+c0+1];
    d = wave_red_sum(d);
    const float beta = 1.f/(1.f+__expf(-d));
    outp[(size_t)n*(RR*HC2) + colofs + c0]     = beta*x.x + (1.f-beta)*o.x;
    outp[(size_t)n*(RR*HC2) + colofs + c0 + 1] = beta*x.y + (1.f-beta)*o.y;
}

extern "C" void kernel_launch(void* const* d_in, const int* in_sizes, int n_in,
                              void* d_out, int out_size, void* d_ws, size_t ws_size,
                              hipStream_t stream)
{
    const float* features = (const float*)d_in[0];
    const int*   n_ids    = (const int*)d_in[1];
    const int*   ei1      = (const int*)d_in[2];
    const int*   ei2      = (const int*)d_in[3];
    const float* wq1 = (const float*)d_in[4];  const float* bq1 = (const float*)d_in[5];
    const float* wk1 = (const float*)d_in[6];  const float* bk1 = (const float*)d_in[7];
    const float* wv1 = (const float*)d_in[8];  const float* bv1 = (const float*)d_in[9];
    const float* ws1 = (const float*)d_in[10]; const float* bs1 = (const float*)d_in[11];
    const float* wbeta1 = (const float*)d_in[12];
    const float* bn_g = (const float*)d_in[13]; const float* bn_b = (const float*)d_in[14];
    const float* bn_m = (const float*)d_in[15]; const float* bn_v = (const float*)d_in[16];
    const float* wq2 = (const float*)d_in[17]; const float* bq2 = (const float*)d_in[18];
    const float* wk2 = (const float*)d_in[19]; const float* bk2 = (const float*)d_in[20];
    const float* wv2 = (const float*)d_in[21]; const float* bv2 = (const float*)d_in[22];
    const float* ws2 = (const float*)d_in[23]; const float* bs2 = (const float*)d_in[24];
    const float* wbeta2 = (const float*)d_in[25];
    float* outp = (float*)d_out;

    char* p = (char*)d_ws;
    auto alloc = [&](size_t bytes) { char* q = p; p += (bytes + 255) & ~(size_t)255; return q; };
    short* k1b  = (short*)alloc(sizeof(short)*(size_t)NN0*HC1);   // 41 MB
    short* v1b  = (short*)alloc(sizeof(short)*(size_t)NN0*HC1);   // 41 MB
    short* q1b  = (short*)alloc(sizeof(short)*(size_t)NN1*HC1);   // 10.2 MB
    float* att1 = (float*)alloc(sizeof(float)*(size_t)NN1*HC1);   // 20.5 MB
    float* xr1  = (float*)alloc(sizeof(float)*(size_t)NN1*HC1);   // 20.5 MB
    float* alpha1 = (float*)alloc(sizeof(float)*(size_t)NE1*2);
    short* xbf  = (short*)alloc(sizeof(short)*(size_t)NTOT*FIN);  // 25.6 MB
    short* wt1  = (short*)alloc(sizeof(short)*(size_t)RR*4*FIN*HC1);
    short* wt2  = (short*)alloc(sizeof(short)*(size_t)RR*4*HC1*HC2);
    int* cnt1   = (int*)alloc(sizeof(int)*NN1);
    int* offs1  = (int*)alloc(sizeof(int)*(NN1+1));
    int* cur1   = (int*)alloc(sizeof(int)*NN1);
    int* elist1 = (int*)alloc(sizeof(int)*NE1);
    int* cnt2   = (int*)alloc(sizeof(int)*NB);
    int* offs2  = (int*)alloc(sizeof(int)*(NB+1));
    int* cur2   = (int*)alloc(sizeof(int)*NB);
    int* elist2 = (int*)alloc(sizeof(int)*NE2);
    // stream-ordered aliases:
    // hbf (bf16 NN1 x HC1, 10.2 MB) lives in k1b region: k1b dead after edge_alpha l1;
    // hbf written by beta_bn_elu, read by layer2 gemms, dead before next replica's kv-gemm.
    short* hbf = (short*)k1b;
    // layer2 f32 buffers (~25 MB) live in v1b region: v1b dead after agg_l1; all written
    // and consumed before next replica rewrites v1b.
    char* vp = (char*)v1b;
    auto valloc = [&](size_t bytes) { char* q = vp; vp += (bytes + 255) & ~(size_t)255; return q; };
    float* k2   = (float*)valloc(sizeof(float)*(size_t)NN1*HC2);
    float* v2   = (float*)valloc(sizeof(float)*(size_t)NN1*HC2);
    float* q2   = (float*)valloc(sizeof(float)*(size_t)NB*HC2);
    float* xr2  = (float*)valloc(sizeof(float)*(size_t)NB*HC2);
    float* alpha2 = (float*)valloc(sizeof(float)*(size_t)NE2);
    (void)ws_size; (void)in_sizes; (void)n_in; (void)out_size;

    // ---- prologue: dtype conversions + fragment packing (once per launch) ----
    fcvt_k<<<(NTOT*FIN/4 + 255)/256, 256, 0, stream>>>(features, xbf, NTOT*FIN/4);
    {
        dim3 g1(128, 4, RR);
        wpack_k<FIN, HC1><<<g1, 256, 0, stream>>>(wq1, wk1, wv1, ws1, wt1);
        dim3 g2(128, 4, RR);
        wpack_k<HC1, HC2><<<g2, 256, 0, stream>>>(wq2, wk2, wv2, ws2, wt2);
    }
    const size_t WSZ = (size_t)FIN*HC1;   // 32768 elems, same for both layers

    for (int r = 0; r < RR; ++r) {
        const int* nid  = n_ids + (size_t)r*NN0;
        const int* src1 = ei1 + (size_t)r*2*NE1;
        const int* dst1 = src1 + NE1;
        const int* src2 = ei2 + (size_t)r*2*NE2;
        const int* dst2 = src2 + NE2;
        const short* ptq1 = wt1 + ((size_t)r*4 + 0)*WSZ;
        const short* ptk1 = wt1 + ((size_t)r*4 + 1)*WSZ;
        const short* ptv1 = wt1 + ((size_t)r*4 + 2)*WSZ;
        const short* pts1 = wt1 + ((size_t)r*4 + 3)*WSZ;
        const short* ptq2 = wt2 + ((size_t)r*4 + 0)*WSZ;
        const short* ptk2 = wt2 + ((size_t)r*4 + 1)*WSZ;
        const short* ptv2 = wt2 + ((size_t)r*4 + 2)*WSZ;
        const short* pts2 = wt2 + ((size_t)r*4 + 3)*WSZ;

        // ---- layer 1 CSR ----
        hipMemsetAsync(cnt1, 0, sizeof(int)*NN1, stream);
        hist_k<<<512, 256, 0, stream>>>(dst1, NE1, cnt1);
        exscan_k<<<1, 256, 0, stream>>>(cnt1, NN1, offs1, cur1);
        scatter_k<<<512, 256, 0, stream>>>(dst1, NE1, cur1, elist1);

        // ---- layer 1 projections (MFMA, fused gather, bf16 out for k/v/q) ----
        gemm2m<FIN, HC1, short, short><<<NN0/64, 256, 0, stream>>>(
            xbf, FIN, nid, NN0, ptk1, bk1 + r*HC1, k1b, ptv1, bv1 + r*HC1, v1b);
        gemm2m<FIN, HC1, short, float><<<(NN1+63)/64, 256, 0, stream>>>(
            xbf, FIN, nid, NN1, ptq1, bq1 + r*HC1, q1b, pts1, bs1 + r*HC1, xr1);

        // ---- layer 1 attention ----
        edge_alpha<HC1, 2, short, short><<<4096, 256, 0, stream>>>(src1, dst1, NE1, q1b, k1b, alpha1);
        agg_l1<<<NN1, 64, 0, stream>>>(offs1, elist1, src1, alpha1, v1b, att1);
        beta_bn_elu<<<NN1, 64, 0, stream>>>(att1, xr1, wbeta1 + (size_t)r*3*HC1,
            bn_g + (size_t)r*HC1, bn_b + (size_t)r*HC1,
            bn_m + (size_t)r*HC1, bn_v + (size_t)r*HC1, hbf);

        // ---- layer 2 CSR ----
        hipMemsetAsync(cnt2, 0, sizeof(int)*NB, stream);
        hist_k<<<256, 256, 0, stream>>>(dst2, NE2, cnt2);
        exscan_k<<<1, 256, 0, stream>>>(cnt2, NB, offs2, cur2);
        scatter_k<<<256, 256, 0, stream>>>(dst2, NE2, cur2, elist2);

        // ---- layer 2 projections (MFMA) ----
        gemm2m<HC1, HC2, float, float><<<(NN1+63)/64, 256, 0, stream>>>(
            hbf, HC1, nullptr, NN1, ptk2, bk2 + r*HC2, k2, ptv2, bv2 + r*HC2, v2);
        gemm2m<HC1, HC2, float, float><<<NB/64, 256, 0, stream>>>(
            hbf, HC1, nullptr, NB, ptq2, bq2 + r*HC2, q2, pts2, bs2 + r*HC2, xr2);

        // ---- layer 2 attention + output ----
        edge_alpha<HC2, 1, float, float><<<1024, 256, 0, stream>>>(src2, dst2, NE2, q2, k2, alpha2);
        agg_l2<<<NB, 64, 0, stream>>>(offs2, elist2, src2, alpha2, v2, q2);
        beta_out<<<NB, 64, 0, stream>>>(q2, xr2, wbeta2 + (size_t)r*3*HC2, outp, r*HC2);
    }
}

// Round 4
// 1044.112 us; speedup vs baseline: 1.8712x; 1.5327x over previous
//
#include <hip/hip_runtime.h>
#include <math.h>

#define RR 3
#define NTOT 100000
#define NN0 80000
#define NN1 20000
#define NB 4096
#define NE1 300000
#define NE2 65536
#define FIN 128
#define HC1 256   // layer1: 2 heads x 128
#define HC2 128   // layer2: 1 head x 128

typedef __attribute__((ext_vector_type(8))) short bf16x8;
typedef __attribute__((ext_vector_type(4))) short s16x4;
typedef __attribute__((ext_vector_type(2))) short s16x2;
typedef __attribute__((ext_vector_type(4))) float f32x4;

__device__ __forceinline__ float wave_red_sum(float v) {
    #pragma unroll
    for (int off = 32; off >= 1; off >>= 1) v += __shfl_xor(v, off, 64);
    return v;
}

__device__ __forceinline__ short f2bf(float x) {
    union { float f; unsigned u; } c; c.f = x;
    unsigned r = c.u + 0x7fffu + ((c.u >> 16) & 1u);
    return (short)(r >> 16);
}
__device__ __forceinline__ float bf2f(short s) {
    union { unsigned u; float f; } c; c.u = ((unsigned)(unsigned short)s) << 16;
    return c.f;
}

// generic 4-elem and 2-elem row loads (f32 or bf16)
__device__ __forceinline__ float4 ld4(const float* p) { return *(const float4*)p; }
__device__ __forceinline__ float4 ld4(const short* p) {
    s16x4 v = *(const s16x4*)p;
    float4 r = { bf2f(v[0]), bf2f(v[1]), bf2f(v[2]), bf2f(v[3]) };
    return r;
}
__device__ __forceinline__ float2 ld2(const float* p) { return *(const float2*)p; }
__device__ __forceinline__ float2 ld2(const short* p) {
    s16x2 v = *(const s16x2*)p;
    float2 r = { bf2f(v[0]), bf2f(v[1]) };
    return r;
}

// ---------- convert features f32 -> bf16 ----------
__global__ void __launch_bounds__(256)
fcvt_k(const float* __restrict__ f, short* __restrict__ o, int n4) {
    int i = blockIdx.x * 256 + threadIdx.x;
    if (i < n4) {
        float4 v = *(const float4*)(f + (size_t)i * 4);
        s16x4 s = { f2bf(v.x), f2bf(v.y), f2bf(v.z), f2bf(v.w) };
        *(s16x4*)(o + (size_t)i * 4) = s;
    }
}

// ---------- pack 4 weight mats per replica into MFMA B-fragment order ----------
// W[K][N] f32 -> P[((nt*KS+ks)*64+lane)*8+j] = bf16(W[ks*32+(lane>>4)*8+j][nt*16+(lane&15)])
template<int K, int N>
__global__ void __launch_bounds__(256)
wpack_k(const float* __restrict__ W0, const float* __restrict__ W1,
        const float* __restrict__ W2, const float* __restrict__ W3,
        short* __restrict__ P) {
    constexpr int KS = K / 32;
    const int m = blockIdx.y, r = blockIdx.z;
    const float* W = (m == 0 ? W0 : m == 1 ? W1 : m == 2 ? W2 : W3) + (size_t)r * K * N;
    short* o = P + ((size_t)(r * 4 + m)) * K * N;
    for (int i = blockIdx.x * 256 + threadIdx.x; i < K * N; i += gridDim.x * 256) {
        int j = i & 7, lane = (i >> 3) & 63, f = i >> 9;
        int ks = f % KS, nt = f / KS;
        int k = ks * 32 + (lane >> 4) * 8 + j;
        int n = nt * 16 + (lane & 15);
        o[i] = f2bf(W[(size_t)k * N + n]);
    }
}

// ---------- MFMA GEMM, low-pressure tiling ----------
// Workgroup (4 waves) computes 32 rows x N for BOTH output mats.
// Wave w owns n-tiles [w*NT/4, (w+1)*NT/4) and both 16-row m-tiles.
// acc = 2*(NT/4)*2*4 VGPRs (64 @ N=256, 32 @ N=128) -> room for load pipelining.
template<int K, int N, typename OT0, typename OT1>
__global__ void __launch_bounds__(256)
gemm2l(const short* __restrict__ xbf, int ldx, const int* __restrict__ gidx,
       const short* __restrict__ P0, const float* __restrict__ b0, OT0* __restrict__ out0,
       const short* __restrict__ P1, const float* __restrict__ b1, OT1* __restrict__ out1)
{
    constexpr int NT = N / 16;    // total n-tiles
    constexpr int NW = NT / 4;    // n-tiles per wave
    constexpr int KS = K / 32;    // k-steps
    constexpr int MT = 2;         // m-tiles per block (32 rows)
    const int lane = threadIdx.x & 63;
    const int wid  = threadIdx.x >> 6;
    const int rowbase = blockIdx.x * (MT * 16);

    // A fragment pointers: lane holds row (lane&15) of each m-tile, k = 8*(lane>>4)+j
    const short* ap[MT];
    #pragma unroll
    for (int mt = 0; mt < MT; ++mt) {
        int arow = rowbase + mt * 16 + (lane & 15);
        int srow = gidx ? gidx[arow] : arow;
        ap[mt] = xbf + (size_t)srow * ldx + ((lane >> 4) * 8);
    }
    const int fb = lane * 8;

    f32x4 acc[MT][NW][2];
    #pragma unroll
    for (int mt = 0; mt < MT; ++mt)
        #pragma unroll
        for (int j = 0; j < NW; ++j) { acc[mt][j][0] = (f32x4)(0.0f); acc[mt][j][1] = (f32x4)(0.0f); }

    for (int ks = 0; ks < KS; ++ks) {
        bf16x8 a[MT];
        #pragma unroll
        for (int mt = 0; mt < MT; ++mt) a[mt] = *(const bf16x8*)(ap[mt] + ks * 32);
        #pragma unroll
        for (int j = 0; j < NW; ++j) {
            const int nt = wid * NW + j;
            const int off = ((nt * KS + ks) << 9) + fb;   // coalesced 1KB wave load
            bf16x8 bv0 = *(const bf16x8*)(P0 + off);
            bf16x8 bv1 = *(const bf16x8*)(P1 + off);
            #pragma unroll
            for (int mt = 0; mt < MT; ++mt) {
                acc[mt][j][0] = __builtin_amdgcn_mfma_f32_16x16x32_bf16(a[mt], bv0, acc[mt][j][0], 0, 0, 0);
                acc[mt][j][1] = __builtin_amdgcn_mfma_f32_16x16x32_bf16(a[mt], bv1, acc[mt][j][1], 0, 0, 0);
            }
        }
    }

    // Epilogue: restage through LDS (padded) -> coalesced vector stores.
    // C/D layout: col = lane&15, row = 4*(lane>>4)+reg  [verified]
    __shared__ float ls[MT * 16][N + 4];
    constexpr int CPT = (MT * 16) * N / 8 / 256;   // 8-elem chunks per thread
    const int tid = threadIdx.x;

    #pragma unroll
    for (int mat = 0; mat < 2; ++mat) {
        if (mat) __syncthreads();   // wait for mat0 reads to finish before overwrite
        const float* bias = mat ? b1 : b0;
        #pragma unroll
        for (int j = 0; j < NW; ++j) {
            const int nt = wid * NW + j;
            const float bb = bias[nt * 16 + (lane & 15)];
            #pragma unroll
            for (int mt = 0; mt < MT; ++mt)
                #pragma unroll
                for (int rg = 0; rg < 4; ++rg)
                    ls[mt * 16 + (lane >> 4) * 4 + rg][nt * 16 + (lane & 15)] =
                        acc[mt][j][mat][rg] + bb;
        }
        __syncthreads();
        #pragma unroll
        for (int c2 = 0; c2 < CPT; ++c2) {
            const int chunk = c2 * 256 + tid;
            const int row = chunk / (N / 8);
            const int colb = (chunk % (N / 8)) * 8;
            float v[8];
            #pragma unroll
            for (int i = 0; i < 8; ++i) v[i] = ls[row][colb + i];
            const size_t gbase = (size_t)(rowbase + row) * N + colb;
            if (mat == 0) {
                if constexpr (sizeof(OT0) == 2) {
                    bf16x8 s;
                    #pragma unroll
                    for (int i = 0; i < 8; ++i) s[i] = f2bf(v[i]);
                    *(bf16x8*)(out0 + gbase) = s;
                } else {
                    float4 lo = { v[0], v[1], v[2], v[3] }, hi = { v[4], v[5], v[6], v[7] };
                    *(float4*)(out0 + gbase) = lo;
                    *(float4*)(out0 + gbase + 4) = hi;
                }
            } else {
                if constexpr (sizeof(OT1) == 2) {
                    bf16x8 s;
                    #pragma unroll
                    for (int i = 0; i < 8; ++i) s[i] = f2bf(v[i]);
                    *(bf16x8*)(out1 + gbase) = s;
                } else {
                    float4 lo = { v[0], v[1], v[2], v[3] }, hi = { v[4], v[5], v[6], v[7] };
                    *(float4*)(out1 + gbase) = lo;
                    *(float4*)(out1 + gbase + 4) = hi;
                }
            }
        }
    }
}

// ---------- per-edge attention logits ----------
template<int HC, int H, typename QT, typename KT>
__global__ void __launch_bounds__(256)
edge_alpha(const int* __restrict__ src, const int* __restrict__ dst, int E,
           const QT* __restrict__ q, const KT* __restrict__ k,
           float* __restrict__ alpha)
{
    constexpr int EPL = HC / 64;
    constexpr int C = HC / H;
    constexpr int GL = 64 / H;
    const int lane = threadIdx.x & 63;
    const int wid = (blockIdx.x * blockDim.x + threadIdx.x) >> 6;
    const int nw = (gridDim.x * blockDim.x) >> 6;
    const float scale = rsqrtf((float)C);
    for (int e = wid; e < E; e += nw) {
        const int s = src[e], d = dst[e];
        const QT* qp = q + (size_t)d * HC + lane * EPL;
        const KT* kp = k + (size_t)s * HC + lane * EPL;
        float part;
        if constexpr (EPL == 4) {
            float4 qv = ld4(qp), kv = ld4(kp);
            part = qv.x*kv.x + qv.y*kv.y + qv.z*kv.z + qv.w*kv.w;
        } else {
            float2 qv = ld2(qp), kv = ld2(kp);
            part = qv.x*kv.x + qv.y*kv.y;
        }
        #pragma unroll
        for (int off = GL/2; off >= 1; off >>= 1) part += __shfl_xor(part, off, 64);
        if ((lane & (GL-1)) == 0)
            alpha[(size_t)e*H + lane/GL] = part * scale;
    }
}

// ---------- CSR helpers ----------
__global__ void hist_k(const int* __restrict__ dst, int E, int* __restrict__ cnt) {
    for (int e = blockIdx.x*blockDim.x + threadIdx.x; e < E; e += gridDim.x*blockDim.x)
        atomicAdd(&cnt[dst[e]], 1);
}
__global__ void __launch_bounds__(256)
exscan_k(const int* __restrict__ cnt, int n, int* __restrict__ offs, int* __restrict__ cur) {
    __shared__ int ps[256];
    const int tid = threadIdx.x;
    const int chunk = (n + 255) / 256;
    const int lo = tid * chunk;
    const int hi = min(lo + chunk, n);
    int s = 0;
    for (int i = lo; i < hi; ++i) s += cnt[i];
    ps[tid] = s;
    __syncthreads();
    for (int off = 1; off < 256; off <<= 1) {
        int v = (tid >= off) ? ps[tid - off] : 0;
        __syncthreads();
        ps[tid] += v;
        __syncthreads();
    }
    int run = (tid == 0) ? 0 : ps[tid - 1];
    for (int i = lo; i < hi; ++i) { offs[i] = run; cur[i] = run; run += cnt[i]; }
    if (tid == 255) offs[n] = ps[255];
}
__global__ void scatter_k(const int* __restrict__ dst, int E, int* __restrict__ cur, int* __restrict__ elist) {
    for (int e = blockIdx.x*blockDim.x + threadIdx.x; e < E; e += gridDim.x*blockDim.x) {
        int pos = atomicAdd(&cur[dst[e]], 1);
        elist[pos] = e;
    }
}

// ---------- per-node softmax-aggregate (layer1: H=2, C=128, v bf16) ----------
__global__ void __launch_bounds__(64)
agg_l1(const int* __restrict__ offs, const int* __restrict__ elist,
       const int* __restrict__ src, const float* __restrict__ alpha,
       const short* __restrict__ v, float* __restrict__ out)
{
    const int n = blockIdx.x;
    const int lane = threadIdx.x;
    const int c0 = lane * 4;
    const int hd = c0 >> 7;
    const int lo = offs[n], hi = offs[n+1];
    float m = -INFINITY;
    for (int i = lo; i < hi; ++i)
        m = fmaxf(m, alpha[(size_t)elist[i]*2 + hd]);
    float s = 0.f;
    float a0=0.f, a1=0.f, a2=0.f, a3=0.f;
    for (int i = lo; i < hi; ++i) {
        int e = elist[i];
        float p = __expf(alpha[(size_t)e*2 + hd] - m);
        s += p;
        const float4 vv = ld4(v + (size_t)src[e]*HC1 + c0);
        a0 = fmaf(p, vv.x, a0); a1 = fmaf(p, vv.y, a1);
        a2 = fmaf(p, vv.z, a2); a3 = fmaf(p, vv.w, a3);
    }
    const float inv = (s > 0.f) ? 1.f/s : 0.f;
    float4 o = { a0*inv, a1*inv, a2*inv, a3*inv };
    *(float4*)(out + (size_t)n*HC1 + c0) = o;
}

// ---------- per-node softmax-aggregate (layer2: H=1, C=128, v f32) ----------
__global__ void __launch_bounds__(64)
agg_l2(const int* __restrict__ offs, const int* __restrict__ elist,
       const int* __restrict__ src, const float* __restrict__ alpha,
       const float* __restrict__ v, float* __restrict__ out)
{
    const int n = blockIdx.x;
    const int lane = threadIdx.x;
    const int c0 = lane * 2;
    const int lo = offs[n], hi = offs[n+1];
    float m = -INFINITY;
    for (int i = lo; i < hi; ++i)
        m = fmaxf(m, alpha[elist[i]]);
    float s = 0.f; float a0=0.f, a1=0.f;
    for (int i = lo; i < hi; ++i) {
        int e = elist[i];
        float p = __expf(alpha[e] - m);
        s += p;
        const float2 vv = *(const float2*)(v + (size_t)src[e]*HC2 + c0);
        a0 = fmaf(p, vv.x, a0); a1 = fmaf(p, vv.y, a1);
    }
    const float inv = (s > 0.f) ? 1.f/s : 0.f;
    float2 o = { a0*inv, a1*inv };
    *(float2*)(out + (size_t)n*HC2 + c0) = o;
}

// ---------- layer1 epilogue: beta gate + BN(eval) + ELU -> bf16 h ----------
__global__ void __launch_bounds__(64)
beta_bn_elu(const float* __restrict__ att, const float* __restrict__ xr,
            const float* __restrict__ wb,
            const float* __restrict__ g, const float* __restrict__ bb,
            const float* __restrict__ mean, const float* __restrict__ var,
            short* __restrict__ hb)
{
    const int n = blockIdx.x;
    const int lane = threadIdx.x;
    const int c0 = lane * 4;
    float4 o4 = *(const float4*)(att + (size_t)n*HC1 + c0);
    float4 x4 = *(const float4*)(xr + (size_t)n*HC1 + c0);
    float oo[4] = {o4.x,o4.y,o4.z,o4.w};
    float xx[4] = {x4.x,x4.y,x4.z,x4.w};
    float d = 0.f;
    #pragma unroll
    for (int j = 0; j < 4; ++j) {
        int c = c0 + j;
        d += oo[j]*wb[c] + xx[j]*wb[HC1 + c] + (oo[j]-xx[j])*wb[2*HC1 + c];
    }
    d = wave_red_sum(d);
    const float beta = 1.f / (1.f + __expf(-d));
    s16x4 hv4;
    #pragma unroll
    for (int j = 0; j < 4; ++j) {
        int c = c0 + j;
        float hv = beta*xx[j] + (1.f-beta)*oo[j];
        hv = (hv - mean[c]) * rsqrtf(var[c] + 1e-5f) * g[c] + bb[c];
        hv = hv > 0.f ? hv : expm1f(hv);
        hv4[j] = f2bf(hv);
    }
    *(s16x4*)(hb + (size_t)n*HC1 + c0) = hv4;
}

// ---------- layer2 epilogue: beta gate + strided output write ----------
__global__ void __launch_bounds__(64)
beta_out(const float* __restrict__ att, const float* __restrict__ xr,
         const float* __restrict__ wb, float* __restrict__ outp, int colofs)
{
    const int n = blockIdx.x;
    const int lane = threadIdx.x;
    const int c0 = lane * 2;
    float2 o = *(const float2*)(att + (size_t)n*HC2 + c0);
    float2 x = *(const float2*)(xr + (size_t)n*HC2 + c0);
    float d = o.x*wb[c0] + o.y*wb[c0+1]
            + x.x*wb[HC2+c0] + x.y*wb[HC2+c0+1]
            + (o.x-x.x)*wb[2*HC2+c0] + (o.y-x.y)*wb[2*HC2+c0+1];
    d = wave_red_sum(d);
    const float beta = 1.f/(1.f+__expf(-d));
    outp[(size_t)n*(RR*HC2) + colofs + c0]     = beta*x.x + (1.f-beta)*o.x;
    outp[(size_t)n*(RR*HC2) + colofs + c0 + 1] = beta*x.y + (1.f-beta)*o.y;
}

extern "C" void kernel_launch(void* const* d_in, const int* in_sizes, int n_in,
                              void* d_out, int out_size, void* d_ws, size_t ws_size,
                              hipStream_t stream)
{
    const float* features = (const float*)d_in[0];
    const int*   n_ids    = (const int*)d_in[1];
    const int*   ei1      = (const int*)d_in[2];
    const int*   ei2      = (const int*)d_in[3];
    const float* wq1 = (const float*)d_in[4];  const float* bq1 = (const float*)d_in[5];
    const float* wk1 = (const float*)d_in[6];  const float* bk1 = (const float*)d_in[7];
    const float* wv1 = (const float*)d_in[8];  const float* bv1 = (const float*)d_in[9];
    const float* ws1 = (const float*)d_in[10]; const float* bs1 = (const float*)d_in[11];
    const float* wbeta1 = (const float*)d_in[12];
    const float* bn_g = (const float*)d_in[13]; const float* bn_b = (const float*)d_in[14];
    const float* bn_m = (const float*)d_in[15]; const float* bn_v = (const float*)d_in[16];
    const float* wq2 = (const float*)d_in[17]; const float* bq2 = (const float*)d_in[18];
    const float* wk2 = (const float*)d_in[19]; const float* bk2 = (const float*)d_in[20];
    const float* wv2 = (const float*)d_in[21]; const float* bv2 = (const float*)d_in[22];
    const float* ws2 = (const float*)d_in[23]; const float* bs2 = (const float*)d_in[24];
    const float* wbeta2 = (const float*)d_in[25];
    float* outp = (float*)d_out;

    char* p = (char*)d_ws;
    auto alloc = [&](size_t bytes) { char* q = p; p += (bytes + 255) & ~(size_t)255; return q; };
    short* k1b  = (short*)alloc(sizeof(short)*(size_t)NN0*HC1);   // 41 MB
    short* v1b  = (short*)alloc(sizeof(short)*(size_t)NN0*HC1);   // 41 MB
    short* q1b  = (short*)alloc(sizeof(short)*(size_t)NN1*HC1);   // 10.2 MB
    float* att1 = (float*)alloc(sizeof(float)*(size_t)NN1*HC1);   // 20.5 MB
    float* xr1  = (float*)alloc(sizeof(float)*(size_t)NN1*HC1);   // 20.5 MB
    float* alpha1 = (float*)alloc(sizeof(float)*(size_t)NE1*2);
    short* xbf  = (short*)alloc(sizeof(short)*(size_t)NTOT*FIN);  // 25.6 MB
    short* wt1  = (short*)alloc(sizeof(short)*(size_t)RR*4*FIN*HC1);
    short* wt2  = (short*)alloc(sizeof(short)*(size_t)RR*4*HC1*HC2);
    int* cnt1   = (int*)alloc(sizeof(int)*NN1);
    int* offs1  = (int*)alloc(sizeof(int)*(NN1+1));
    int* cur1   = (int*)alloc(sizeof(int)*NN1);
    int* elist1 = (int*)alloc(sizeof(int)*NE1);
    int* cnt2   = (int*)alloc(sizeof(int)*NB);
    int* offs2  = (int*)alloc(sizeof(int)*(NB+1));
    int* cur2   = (int*)alloc(sizeof(int)*NB);
    int* elist2 = (int*)alloc(sizeof(int)*NE2);
    // stream-ordered aliases (same liveness argument as round 3):
    short* hbf = (short*)k1b;
    char* vp = (char*)v1b;
    auto valloc = [&](size_t bytes) { char* q = vp; vp += (bytes + 255) & ~(size_t)255; return q; };
    float* k2   = (float*)valloc(sizeof(float)*(size_t)NN1*HC2);
    float* v2   = (float*)valloc(sizeof(float)*(size_t)NN1*HC2);
    float* q2   = (float*)valloc(sizeof(float)*(size_t)NB*HC2);
    float* xr2  = (float*)valloc(sizeof(float)*(size_t)NB*HC2);
    float* alpha2 = (float*)valloc(sizeof(float)*(size_t)NE2);
    (void)ws_size; (void)in_sizes; (void)n_in; (void)out_size;

    // ---- prologue: dtype conversions + fragment packing (once per launch) ----
    fcvt_k<<<(NTOT*FIN/4 + 255)/256, 256, 0, stream>>>(features, xbf, NTOT*FIN/4);
    {
        dim3 g1(128, 4, RR);
        wpack_k<FIN, HC1><<<g1, 256, 0, stream>>>(wq1, wk1, wv1, ws1, wt1);
        dim3 g2(128, 4, RR);
        wpack_k<HC1, HC2><<<g2, 256, 0, stream>>>(wq2, wk2, wv2, ws2, wt2);
    }
    const size_t WSZ = (size_t)FIN*HC1;   // 32768 elems, same for both layers

    for (int r = 0; r < RR; ++r) {
        const int* nid  = n_ids + (size_t)r*NN0;
        const int* src1 = ei1 + (size_t)r*2*NE1;
        const int* dst1 = src1 + NE1;
        const int* src2 = ei2 + (size_t)r*2*NE2;
        const int* dst2 = src2 + NE2;
        const short* ptq1 = wt1 + ((size_t)r*4 + 0)*WSZ;
        const short* ptk1 = wt1 + ((size_t)r*4 + 1)*WSZ;
        const short* ptv1 = wt1 + ((size_t)r*4 + 2)*WSZ;
        const short* pts1 = wt1 + ((size_t)r*4 + 3)*WSZ;
        const short* ptq2 = wt2 + ((size_t)r*4 + 0)*WSZ;
        const short* ptk2 = wt2 + ((size_t)r*4 + 1)*WSZ;
        const short* ptv2 = wt2 + ((size_t)r*4 + 2)*WSZ;
        const short* pts2 = wt2 + ((size_t)r*4 + 3)*WSZ;

        // ---- layer 1 CSR ----
        hipMemsetAsync(cnt1, 0, sizeof(int)*NN1, stream);
        hist_k<<<512, 256, 0, stream>>>(dst1, NE1, cnt1);
        exscan_k<<<1, 256, 0, stream>>>(cnt1, NN1, offs1, cur1);
        scatter_k<<<512, 256, 0, stream>>>(dst1, NE1, cur1, elist1);

        // ---- layer 1 projections (MFMA, fused gather, bf16 out for k/v/q) ----
        gemm2l<FIN, HC1, short, short><<<NN0/32, 256, 0, stream>>>(
            xbf, FIN, nid, ptk1, bk1 + r*HC1, k1b, ptv1, bv1 + r*HC1, v1b);
        gemm2l<FIN, HC1, short, float><<<NN1/32, 256, 0, stream>>>(
            xbf, FIN, nid, ptq1, bq1 + r*HC1, q1b, pts1, bs1 + r*HC1, xr1);

        // ---- layer 1 attention ----
        edge_alpha<HC1, 2, short, short><<<4096, 256, 0, stream>>>(src1, dst1, NE1, q1b, k1b, alpha1);
        agg_l1<<<NN1, 64, 0, stream>>>(offs1, elist1, src1, alpha1, v1b, att1);
        beta_bn_elu<<<NN1, 64, 0, stream>>>(att1, xr1, wbeta1 + (size_t)r*3*HC1,
            bn_g + (size_t)r*HC1, bn_b + (size_t)r*HC1,
            bn_m + (size_t)r*HC1, bn_v + (size_t)r*HC1, hbf);

        // ---- layer 2 CSR ----
        hipMemsetAsync(cnt2, 0, sizeof(int)*NB, stream);
        hist_k<<<256, 256, 0, stream>>>(dst2, NE2, cnt2);
        exscan_k<<<1, 256, 0, stream>>>(cnt2, NB, offs2, cur2);
        scatter_k<<<256, 256, 0, stream>>>(dst2, NE2, cur2, elist2);

        // ---- layer 2 projections (MFMA) ----
        gemm2l<HC1, HC2, float, float><<<NN1/32, 256, 0, stream>>>(
            hbf, HC1, nullptr, ptk2, bk2 + r*HC2, k2, ptv2, bv2 + r*HC2, v2);
        gemm2l<HC1, HC2, float, float><<<NB/32, 256, 0, stream>>>(
            hbf, HC1, nullptr, ptq2, bq2 + r*HC2, q2, pts2, bs2 + r*HC2, xr2);

        // ---- layer 2 attention + output ----
        edge_alpha<HC2, 1, float, float><<<1024, 256, 0, stream>>>(src2, dst2, NE2, q2, k2, alpha2);
        agg_l2<<<NB, 64, 0, stream>>>(offs2, elist2, src2, alpha2, v2, q2);
        beta_out<<<NB, 64, 0, stream>>>(q2, xr2, wbeta2 + (size_t)r*3*HC2, outp, r*HC2);
    }
}

// Round 5
// 772.446 us; speedup vs baseline: 2.5293x; 1.3517x over previous
//
#include <hip/hip_runtime.h>
#include <math.h>

#define RR 3
#define NTOT 100000
#define NN0 80000
#define NN1 20000
#define NB 4096
#define NE1 300000
#define NE2 65536
#define FIN 128
#define HC1 256   // layer1: 2 heads x 128
#define HC2 128   // layer2: 1 head x 128

typedef __attribute__((ext_vector_type(8))) short bf16x8;
typedef __attribute__((ext_vector_type(4))) short s16x4;
typedef __attribute__((ext_vector_type(2))) short s16x2;
typedef __attribute__((ext_vector_type(4))) float f32x4;

__device__ __forceinline__ float wave_red_sum(float v) {
    #pragma unroll
    for (int off = 32; off >= 1; off >>= 1) v += __shfl_xor(v, off, 64);
    return v;
}

__device__ __forceinline__ short f2bf(float x) {
    union { float f; unsigned u; } c; c.f = x;
    unsigned r = c.u + 0x7fffu + ((c.u >> 16) & 1u);
    return (short)(r >> 16);
}
__device__ __forceinline__ float bf2f(short s) {
    union { unsigned u; float f; } c; c.u = ((unsigned)(unsigned short)s) << 16;
    return c.f;
}

__device__ __forceinline__ float4 ld4(const float* p) { return *(const float4*)p; }
__device__ __forceinline__ float4 ld4(const short* p) {
    s16x4 v = *(const s16x4*)p;
    float4 r = { bf2f(v[0]), bf2f(v[1]), bf2f(v[2]), bf2f(v[3]) };
    return r;
}
__device__ __forceinline__ float2 ld2(const float* p) { return *(const float2*)p; }
__device__ __forceinline__ float2 ld2(const short* p) {
    s16x2 v = *(const s16x2*)p;
    float2 r = { bf2f(v[0]), bf2f(v[1]) };
    return r;
}

// ---------- convert features f32 -> bf16 ----------
__global__ void __launch_bounds__(256)
fcvt_k(const float* __restrict__ f, short* __restrict__ o, int n4) {
    int i = blockIdx.x * 256 + threadIdx.x;
    if (i < n4) {
        float4 v = *(const float4*)(f + (size_t)i * 4);
        s16x4 s = { f2bf(v.x), f2bf(v.y), f2bf(v.z), f2bf(v.w) };
        *(s16x4*)(o + (size_t)i * 4) = s;
    }
}

// ---------- pack 4 weight mats per replica into MFMA B-fragment order ----------
template<int K, int N>
__global__ void __launch_bounds__(256)
wpack_k(const float* __restrict__ W0, const float* __restrict__ W1,
        const float* __restrict__ W2, const float* __restrict__ W3,
        short* __restrict__ P) {
    constexpr int KS = K / 32;
    const int m = blockIdx.y, r = blockIdx.z;
    const float* W = (m == 0 ? W0 : m == 1 ? W1 : m == 2 ? W2 : W3) + (size_t)r * K * N;
    short* o = P + ((size_t)(r * 4 + m)) * K * N;
    for (int i = blockIdx.x * 256 + threadIdx.x; i < K * N; i += gridDim.x * 256) {
        int j = i & 7, lane = (i >> 3) & 63, f = i >> 9;
        int ks = f % KS, nt = f / KS;
        int k = ks * 32 + (lane >> 4) * 8 + j;
        int n = nt * 16 + (lane & 15);
        o[i] = f2bf(W[(size_t)k * N + n]);
    }
}

// ---------- MFMA GEMM, low-pressure tiling (unchanged from round 4) ----------
template<int K, int N, typename OT0, typename OT1>
__global__ void __launch_bounds__(256)
gemm2l(const short* __restrict__ xbf, int ldx, const int* __restrict__ gidx,
       const short* __restrict__ P0, const float* __restrict__ b0, OT0* __restrict__ out0,
       const short* __restrict__ P1, const float* __restrict__ b1, OT1* __restrict__ out1)
{
    constexpr int NT = N / 16;
    constexpr int NW = NT / 4;
    constexpr int KS = K / 32;
    constexpr int MT = 2;
    const int lane = threadIdx.x & 63;
    const int wid  = threadIdx.x >> 6;
    const int rowbase = blockIdx.x * (MT * 16);

    const short* ap[MT];
    #pragma unroll
    for (int mt = 0; mt < MT; ++mt) {
        int arow = rowbase + mt * 16 + (lane & 15);
        int srow = gidx ? gidx[arow] : arow;
        ap[mt] = xbf + (size_t)srow * ldx + ((lane >> 4) * 8);
    }
    const int fb = lane * 8;

    f32x4 acc[MT][NW][2];
    #pragma unroll
    for (int mt = 0; mt < MT; ++mt)
        #pragma unroll
        for (int j = 0; j < NW; ++j) { acc[mt][j][0] = (f32x4)(0.0f); acc[mt][j][1] = (f32x4)(0.0f); }

    for (int ks = 0; ks < KS; ++ks) {
        bf16x8 a[MT];
        #pragma unroll
        for (int mt = 0; mt < MT; ++mt) a[mt] = *(const bf16x8*)(ap[mt] + ks * 32);
        #pragma unroll
        for (int j = 0; j < NW; ++j) {
            const int nt = wid * NW + j;
            const int off = ((nt * KS + ks) << 9) + fb;
            bf16x8 bv0 = *(const bf16x8*)(P0 + off);
            bf16x8 bv1 = *(const bf16x8*)(P1 + off);
            #pragma unroll
            for (int mt = 0; mt < MT; ++mt) {
                acc[mt][j][0] = __builtin_amdgcn_mfma_f32_16x16x32_bf16(a[mt], bv0, acc[mt][j][0], 0, 0, 0);
                acc[mt][j][1] = __builtin_amdgcn_mfma_f32_16x16x32_bf16(a[mt], bv1, acc[mt][j][1], 0, 0, 0);
            }
        }
    }

    __shared__ float ls[MT * 16][N + 4];
    constexpr int CPT = (MT * 16) * N / 8 / 256;
    const int tid = threadIdx.x;

    #pragma unroll
    for (int mat = 0; mat < 2; ++mat) {
        if (mat) __syncthreads();
        const float* bias = mat ? b1 : b0;
        #pragma unroll
        for (int j = 0; j < NW; ++j) {
            const int nt = wid * NW + j;
            const float bb = bias[nt * 16 + (lane & 15)];
            #pragma unroll
            for (int mt = 0; mt < MT; ++mt)
                #pragma unroll
                for (int rg = 0; rg < 4; ++rg)
                    ls[mt * 16 + (lane >> 4) * 4 + rg][nt * 16 + (lane & 15)] =
                        acc[mt][j][mat][rg] + bb;
        }
        __syncthreads();
        #pragma unroll
        for (int c2 = 0; c2 < CPT; ++c2) {
            const int chunk = c2 * 256 + tid;
            const int row = chunk / (N / 8);
            const int colb = (chunk % (N / 8)) * 8;
            float v[8];
            #pragma unroll
            for (int i = 0; i < 8; ++i) v[i] = ls[row][colb + i];
            const size_t gbase = (size_t)(rowbase + row) * N + colb;
            if (mat == 0) {
                if constexpr (sizeof(OT0) == 2) {
                    bf16x8 s;
                    #pragma unroll
                    for (int i = 0; i < 8; ++i) s[i] = f2bf(v[i]);
                    *(bf16x8*)(out0 + gbase) = s;
                } else {
                    float4 lo = { v[0], v[1], v[2], v[3] }, hi = { v[4], v[5], v[6], v[7] };
                    *(float4*)(out0 + gbase) = lo;
                    *(float4*)(out0 + gbase + 4) = hi;
                }
            } else {
                if constexpr (sizeof(OT1) == 2) {
                    bf16x8 s;
                    #pragma unroll
                    for (int i = 0; i < 8; ++i) s[i] = f2bf(v[i]);
                    *(bf16x8*)(out1 + gbase) = s;
                } else {
                    float4 lo = { v[0], v[1], v[2], v[3] }, hi = { v[4], v[5], v[6], v[7] };
                    *(float4*)(out1 + gbase) = lo;
                    *(float4*)(out1 + gbase + 4) = hi;
                }
            }
        }
    }
}

// ---------- CSR helpers (scatter now stores src id directly) ----------
__global__ void hist_k(const int* __restrict__ dst, int E, int* __restrict__ cnt) {
    for (int e = blockIdx.x*blockDim.x + threadIdx.x; e < E; e += gridDim.x*blockDim.x)
        atomicAdd(&cnt[dst[e]], 1);
}
__global__ void __launch_bounds__(256)
exscan_k(const int* __restrict__ cnt, int n, int* __restrict__ offs, int* __restrict__ cur) {
    __shared__ int ps[256];
    const int tid = threadIdx.x;
    const int chunk = (n + 255) / 256;
    const int lo = tid * chunk;
    const int hi = min(lo + chunk, n);
    int s = 0;
    for (int i = lo; i < hi; ++i) s += cnt[i];
    ps[tid] = s;
    __syncthreads();
    for (int off = 1; off < 256; off <<= 1) {
        int v = (tid >= off) ? ps[tid - off] : 0;
        __syncthreads();
        ps[tid] += v;
        __syncthreads();
    }
    int run = (tid == 0) ? 0 : ps[tid - 1];
    for (int i = lo; i < hi; ++i) { offs[i] = run; cur[i] = run; run += cnt[i]; }
    if (tid == 255) offs[n] = ps[255];
}
__global__ void scatter_k(const int* __restrict__ src, const int* __restrict__ dst, int E,
                          int* __restrict__ cur, int* __restrict__ slist) {
    for (int e = blockIdx.x*blockDim.x + threadIdx.x; e < E; e += gridDim.x*blockDim.x) {
        int pos = atomicAdd(&cur[dst[e]], 1);
        slist[pos] = src[e];
    }
}

// ---------- fused layer-1 attention: online softmax + beta gate + BN + ELU ----------
// one wave per dst node; lane owns 4 channels (lanes 0-31 head0, 32-63 head1)
__global__ void __launch_bounds__(64)
attn1_k(const int* __restrict__ offs, const int* __restrict__ slist,
        const short* __restrict__ qb, const short* __restrict__ kb, const short* __restrict__ vb,
        const float* __restrict__ xr, const float* __restrict__ wb,
        const float* __restrict__ g, const float* __restrict__ bbn,
        const float* __restrict__ mean, const float* __restrict__ var,
        short* __restrict__ hb)
{
    const int n = blockIdx.x;
    const int lane = threadIdx.x;
    const int c0 = lane * 4;
    const int lo = offs[n], hi = offs[n+1];
    const float4 q = ld4(qb + (size_t)n * HC1 + c0);
    const float scale = 0.088388347648318447f;   // 1/sqrt(128)

    float m = -INFINITY, s = 0.f;
    float a0 = 0.f, a1 = 0.f, a2 = 0.f, a3 = 0.f;
    float4 kc, vc;
    if (lo < hi) {
        int sr = slist[lo];
        kc = ld4(kb + (size_t)sr * HC1 + c0);
        vc = ld4(vb + (size_t)sr * HC1 + c0);
    }
    for (int i = lo; i < hi; ++i) {
        float4 kn, vn;
        if (i + 1 < hi) {                          // prefetch next edge's rows
            int sr = slist[i + 1];
            kn = ld4(kb + (size_t)sr * HC1 + c0);
            vn = ld4(vb + (size_t)sr * HC1 + c0);
        }
        float part = q.x*kc.x + q.y*kc.y + q.z*kc.z + q.w*kc.w;
        #pragma unroll
        for (int off = 16; off >= 1; off >>= 1) part += __shfl_xor(part, off, 64);
        const float alpha = part * scale;          // per-head (32-lane group) value
        const float mn = fmaxf(m, alpha);
        const float rs = __expf(m - mn);           // m=-inf first iter -> 0
        const float p  = __expf(alpha - mn);
        s  = s*rs + p;
        a0 = a0*rs + p*vc.x; a1 = a1*rs + p*vc.y;
        a2 = a2*rs + p*vc.z; a3 = a3*rs + p*vc.w;
        m = mn;
        kc = kn; vc = vn;
    }
    const float inv = (s > 0.f) ? 1.f/s : 0.f;
    const float att[4] = { a0*inv, a1*inv, a2*inv, a3*inv };

    // beta gate
    const float4 x4 = ld4(xr + (size_t)n * HC1 + c0);
    const float xx[4] = { x4.x, x4.y, x4.z, x4.w };
    float d = 0.f;
    #pragma unroll
    for (int j = 0; j < 4; ++j) {
        int c = c0 + j;
        d += att[j]*wb[c] + xx[j]*wb[HC1 + c] + (att[j]-xx[j])*wb[2*HC1 + c];
    }
    d = wave_red_sum(d);
    const float beta = 1.f / (1.f + __expf(-d));
    s16x4 hv4;
    #pragma unroll
    for (int j = 0; j < 4; ++j) {
        int c = c0 + j;
        float hv = beta*xx[j] + (1.f-beta)*att[j];
        hv = (hv - mean[c]) * rsqrtf(var[c] + 1e-5f) * g[c] + bbn[c];
        hv = hv > 0.f ? hv : expm1f(hv);
        hv4[j] = f2bf(hv);
    }
    *(s16x4*)(hb + (size_t)n * HC1 + c0) = hv4;
}

// ---------- fused layer-2 attention: online softmax + beta gate + strided out ----------
// one wave per dst node; lane owns 2 channels; single head -> full-64-lane dot
__global__ void __launch_bounds__(64)
attn2_k(const int* __restrict__ offs, const int* __restrict__ slist,
        const short* __restrict__ qb, const short* __restrict__ kb, const short* __restrict__ vb,
        const float* __restrict__ xr, const float* __restrict__ wb,
        float* __restrict__ outp, int colofs)
{
    const int n = blockIdx.x;
    const int lane = threadIdx.x;
    const int c0 = lane * 2;
    const int lo = offs[n], hi = offs[n+1];
    const float2 q = ld2(qb + (size_t)n * HC2 + c0);
    const float scale = 0.088388347648318447f;   // 1/sqrt(128)

    float m = -INFINITY, s = 0.f;
    float a0 = 0.f, a1 = 0.f;
    float2 kc, vc;
    if (lo < hi) {
        int sr = slist[lo];
        kc = ld2(kb + (size_t)sr * HC2 + c0);
        vc = ld2(vb + (size_t)sr * HC2 + c0);
    }
    for (int i = lo; i < hi; ++i) {
        float2 kn, vn;
        if (i + 1 < hi) {
            int sr = slist[i + 1];
            kn = ld2(kb + (size_t)sr * HC2 + c0);
            vn = ld2(vb + (size_t)sr * HC2 + c0);
        }
        float part = q.x*kc.x + q.y*kc.y;
        #pragma unroll
        for (int off = 32; off >= 1; off >>= 1) part += __shfl_xor(part, off, 64);
        const float alpha = part * scale;
        const float mn = fmaxf(m, alpha);
        const float rs = __expf(m - mn);
        const float p  = __expf(alpha - mn);
        s  = s*rs + p;
        a0 = a0*rs + p*vc.x; a1 = a1*rs + p*vc.y;
        m = mn;
        kc = kn; vc = vn;
    }
    const float inv = (s > 0.f) ? 1.f/s : 0.f;
    const float att0 = a0*inv, att1 = a1*inv;

    const float2 x2 = ld2(xr + (size_t)n * HC2 + c0);
    float d = att0*wb[c0] + att1*wb[c0+1]
            + x2.x*wb[HC2+c0] + x2.y*wb[HC2+c0+1]
            + (att0-x2.x)*wb[2*HC2+c0] + (att1-x2.y)*wb[2*HC2+c0+1];
    d = wave_red_sum(d);
    const float beta = 1.f/(1.f+__expf(-d));
    outp[(size_t)n*(RR*HC2) + colofs + c0]     = beta*x2.x + (1.f-beta)*att0;
    outp[(size_t)n*(RR*HC2) + colofs + c0 + 1] = beta*x2.y + (1.f-beta)*att1;
}

extern "C" void kernel_launch(void* const* d_in, const int* in_sizes, int n_in,
                              void* d_out, int out_size, void* d_ws, size_t ws_size,
                              hipStream_t stream)
{
    const float* features = (const float*)d_in[0];
    const int*   n_ids    = (const int*)d_in[1];
    const int*   ei1      = (const int*)d_in[2];
    const int*   ei2      = (const int*)d_in[3];
    const float* wq1 = (const float*)d_in[4];  const float* bq1 = (const float*)d_in[5];
    const float* wk1 = (const float*)d_in[6];  const float* bk1 = (const float*)d_in[7];
    const float* wv1 = (const float*)d_in[8];  const float* bv1 = (const float*)d_in[9];
    const float* ws1 = (const float*)d_in[10]; const float* bs1 = (const float*)d_in[11];
    const float* wbeta1 = (const float*)d_in[12];
    const float* bn_g = (const float*)d_in[13]; const float* bn_b = (const float*)d_in[14];
    const float* bn_m = (const float*)d_in[15]; const float* bn_v = (const float*)d_in[16];
    const float* wq2 = (const float*)d_in[17]; const float* bq2 = (const float*)d_in[18];
    const float* wk2 = (const float*)d_in[19]; const float* bk2 = (const float*)d_in[20];
    const float* wv2 = (const float*)d_in[21]; const float* bv2 = (const float*)d_in[22];
    const float* ws2 = (const float*)d_in[23]; const float* bs2 = (const float*)d_in[24];
    const float* wbeta2 = (const float*)d_in[25];
    float* outp = (float*)d_out;

    char* p = (char*)d_ws;
    auto alloc = [&](size_t bytes) { char* q = p; p += (bytes + 255) & ~(size_t)255; return q; };
    short* k1b  = (short*)alloc(sizeof(short)*(size_t)NN0*HC1);   // 41 MB
    short* v1b  = (short*)alloc(sizeof(short)*(size_t)NN0*HC1);   // 41 MB
    short* q1b  = (short*)alloc(sizeof(short)*(size_t)NN1*HC1);   // 10.2 MB
    float* xr1  = (float*)alloc(sizeof(float)*(size_t)NN1*HC1);   // 20.5 MB
    short* hbf  = (short*)alloc(sizeof(short)*(size_t)NN1*HC1);   // 10.2 MB
    short* xbf  = (short*)alloc(sizeof(short)*(size_t)NTOT*FIN);  // 25.6 MB
    short* wt1  = (short*)alloc(sizeof(short)*(size_t)RR*4*FIN*HC1);
    short* wt2  = (short*)alloc(sizeof(short)*(size_t)RR*4*HC1*HC2);
    short* k2b  = (short*)alloc(sizeof(short)*(size_t)NN1*HC2);
    short* v2b  = (short*)alloc(sizeof(short)*(size_t)NN1*HC2);
    short* q2b  = (short*)alloc(sizeof(short)*(size_t)NB*HC2);
    float* xr2  = (float*)alloc(sizeof(float)*(size_t)NB*HC2);
    int* cnt1   = (int*)alloc(sizeof(int)*NN1);
    int* offs1  = (int*)alloc(sizeof(int)*(NN1+1));
    int* cur1   = (int*)alloc(sizeof(int)*NN1);
    int* slist1 = (int*)alloc(sizeof(int)*NE1);
    int* cnt2   = (int*)alloc(sizeof(int)*NB);
    int* offs2  = (int*)alloc(sizeof(int)*(NB+1));
    int* cur2   = (int*)alloc(sizeof(int)*NB);
    int* slist2 = (int*)alloc(sizeof(int)*NE2);
    (void)ws_size; (void)in_sizes; (void)n_in; (void)out_size;

    // ---- prologue: dtype conversions + fragment packing (once per launch) ----
    fcvt_k<<<(NTOT*FIN/4 + 255)/256, 256, 0, stream>>>(features, xbf, NTOT*FIN/4);
    {
        dim3 g1(128, 4, RR);
        wpack_k<FIN, HC1><<<g1, 256, 0, stream>>>(wq1, wk1, wv1, ws1, wt1);
        dim3 g2(128, 4, RR);
        wpack_k<HC1, HC2><<<g2, 256, 0, stream>>>(wq2, wk2, wv2, ws2, wt2);
    }
    const size_t WSZ = (size_t)FIN*HC1;

    for (int r = 0; r < RR; ++r) {
        const int* nid  = n_ids + (size_t)r*NN0;
        const int* src1 = ei1 + (size_t)r*2*NE1;
        const int* dst1 = src1 + NE1;
        const int* src2 = ei2 + (size_t)r*2*NE2;
        const int* dst2 = src2 + NE2;
        const short* ptq1 = wt1 + ((size_t)r*4 + 0)*WSZ;
        const short* ptk1 = wt1 + ((size_t)r*4 + 1)*WSZ;
        const short* ptv1 = wt1 + ((size_t)r*4 + 2)*WSZ;
        const short* pts1 = wt1 + ((size_t)r*4 + 3)*WSZ;
        const short* ptq2 = wt2 + ((size_t)r*4 + 0)*WSZ;
        const short* ptk2 = wt2 + ((size_t)r*4 + 1)*WSZ;
        const short* ptv2 = wt2 + ((size_t)r*4 + 2)*WSZ;
        const short* pts2 = wt2 + ((size_t)r*4 + 3)*WSZ;

        // ---- layer 1 CSR ----
        hipMemsetAsync(cnt1, 0, sizeof(int)*NN1, stream);
        hist_k<<<512, 256, 0, stream>>>(dst1, NE1, cnt1);
        exscan_k<<<1, 256, 0, stream>>>(cnt1, NN1, offs1, cur1);
        scatter_k<<<512, 256, 0, stream>>>(src1, dst1, NE1, cur1, slist1);

        // ---- layer 1 projections (MFMA, fused gather, bf16 out) ----
        gemm2l<FIN, HC1, short, short><<<NN0/32, 256, 0, stream>>>(
            xbf, FIN, nid, ptk1, bk1 + r*HC1, k1b, ptv1, bv1 + r*HC1, v1b);
        gemm2l<FIN, HC1, short, float><<<NN1/32, 256, 0, stream>>>(
            xbf, FIN, nid, ptq1, bq1 + r*HC1, q1b, pts1, bs1 + r*HC1, xr1);

        // ---- layer 1 fused attention + epilogue ----
        attn1_k<<<NN1, 64, 0, stream>>>(offs1, slist1, q1b, k1b, v1b, xr1,
            wbeta1 + (size_t)r*3*HC1,
            bn_g + (size_t)r*HC1, bn_b + (size_t)r*HC1,
            bn_m + (size_t)r*HC1, bn_v + (size_t)r*HC1, hbf);

        // ---- layer 2 CSR ----
        hipMemsetAsync(cnt2, 0, sizeof(int)*NB, stream);
        hist_k<<<256, 256, 0, stream>>>(dst2, NE2, cnt2);
        exscan_k<<<1, 256, 0, stream>>>(cnt2, NB, offs2, cur2);
        scatter_k<<<256, 256, 0, stream>>>(src2, dst2, NE2, cur2, slist2);

        // ---- layer 2 projections (MFMA, bf16 out for k/v/q) ----
        gemm2l<HC1, HC2, short, short><<<NN1/32, 256, 0, stream>>>(
            hbf, HC1, nullptr, ptk2, bk2 + r*HC2, k2b, ptv2, bv2 + r*HC2, v2b);
        gemm2l<HC1, HC2, short, float><<<NB/32, 256, 0, stream>>>(
            hbf, HC1, nullptr, ptq2, bq2 + r*HC2, q2b, pts2, bs2 + r*HC2, xr2);

        // ---- layer 2 fused attention + output ----
        attn2_k<<<NB, 64, 0, stream>>>(offs2, slist2, q2b, k2b, v2b, xr2,
            wbeta2 + (size_t)r*3*HC2, outp, r*HC2);
    }
}